// Round 2
// baseline (1435.616 us; speedup 1.0000x reference)
//
#include <hip/hip_runtime.h>
#include <math.h>

typedef __attribute__((ext_vector_type(8))) short short8;
typedef __attribute__((ext_vector_type(4))) float f32x4;
typedef __attribute__((ext_vector_type(4))) float f4;
typedef __attribute__((ext_vector_type(4))) unsigned short us4;
typedef unsigned short u16;

#define Bn 32
#define Ln 128
#define Dn 512
#define LATn 256
#define Vn 50257
#define VPAD 50304
#define DFn 2048
#define Hn 8
#define HDn 64

__device__ __forceinline__ u16 f2bf(float f) {
  union { float f; unsigned u; } v; v.f = f;
  unsigned r = 0x7FFFu + ((v.u >> 16) & 1u);
  return (u16)((v.u + r) >> 16);
}
__device__ __forceinline__ float bf2f(u16 u) {
  union { unsigned u; float f; } v; v.u = ((unsigned)u) << 16;
  return v.f;
}

// ---------------- f32 -> bf16 conversion (weights), zero-padded tail ---------
__global__ void k_cvt_bf16(const f4* __restrict__ in, us4* __restrict__ out,
                           int n4, int n4pad) {
  int i = blockIdx.x * blockDim.x + threadIdx.x;
  int stride = gridDim.x * blockDim.x;
  for (; i < n4pad; i += stride) {
    us4 o;
    if (i < n4) {
      f4 v = in[i];
      o[0] = f2bf(v[0]); o[1] = f2bf(v[1]); o[2] = f2bf(v[2]); o[3] = f2bf(v[3]);
    } else {
      o[0] = 0; o[1] = 0; o[2] = 0; o[3] = 0;
    }
    out[i] = o;
  }
}

// ---------------- latent_proj: mem = LN(GELU(z @ lp_w.T + lp_b)) -------------
__global__ __launch_bounds__(256)
void k_latent_mem(const float* __restrict__ z, const float* __restrict__ lp_w,
                  const float* __restrict__ lp_b, const float* __restrict__ g,
                  const float* __restrict__ be, float* __restrict__ mem) {
  __shared__ float zs[LATn];
  __shared__ float red[16];
  int b = blockIdx.x, t = threadIdx.x;
  zs[t] = z[b * LATn + t];
  __syncthreads();
  float h[2];
  #pragma unroll
  for (int j = 0; j < 2; j++) {
    int oj = t + j * 256;
    const float* w = lp_w + (size_t)oj * LATn;
    float s0 = 0, s1 = 0, s2 = 0, s3 = 0;
    for (int k = 0; k < LATn; k += 4) {
      s0 += zs[k] * w[k]; s1 += zs[k+1] * w[k+1];
      s2 += zs[k+2] * w[k+2]; s3 += zs[k+3] * w[k+3];
    }
    float x = s0 + s1 + s2 + s3 + lp_b[oj];
    h[j] = 0.5f * x * (1.0f + erff(x * 0.70710678118654752f));
  }
  float sum = h[0] + h[1], sq = h[0]*h[0] + h[1]*h[1];
  for (int off = 32; off; off >>= 1) {
    sum += __shfl_down(sum, off, 64);
    sq  += __shfl_down(sq,  off, 64);
  }
  int lane = t & 63, wid = t >> 6;
  if (!lane) { red[wid] = sum; red[8 + wid] = sq; }
  __syncthreads();
  float ts = red[0] + red[1] + red[2] + red[3];
  float tq = red[8] + red[9] + red[10] + red[11];
  float mu = ts * (1.0f / Dn);
  float var = tq * (1.0f / Dn) - mu * mu;
  float rstd = rsqrtf(fmaxf(var, 0.0f) + 1e-5f);
  #pragma unroll
  for (int j = 0; j < 2; j++) {
    int oj = t + j * 256;
    mem[b * Dn + oj] = (h[j] - mu) * rstd * g[oj] + be[oj];
  }
}

// ------------- cross-attention precompute (Lk=1 => softmax==1 => o = v) ------
__global__ __launch_bounds__(256)
void k_ca(const float* __restrict__ mem, const float* __restrict__ ca_qkv_w,
          const float* __restrict__ ca_qkv_b, const float* __restrict__ ca_out_w,
          const float* __restrict__ ca_out_b, float* __restrict__ ca_add) {
  int blk = blockIdx.x;
  int i = blk >> 5, b = blk & 31, t = threadIdx.x;
  __shared__ float ms[Dn];
  __shared__ float vs[Dn];
  ms[t] = mem[b * Dn + t];
  ms[t + 256] = mem[b * Dn + t + 256];
  __syncthreads();
  const float* wv = ca_qkv_w + ((size_t)i * 1536 + 1024) * Dn;
  const float* bv = ca_qkv_b + i * 1536 + 1024;
  for (int j = t; j < Dn; j += 256) {
    const float* w = wv + (size_t)j * Dn;
    float s0 = 0, s1 = 0, s2 = 0, s3 = 0;
    for (int k = 0; k < Dn; k += 4) {
      s0 += ms[k]*w[k]; s1 += ms[k+1]*w[k+1]; s2 += ms[k+2]*w[k+2]; s3 += ms[k+3]*w[k+3];
    }
    vs[j] = s0 + s1 + s2 + s3 + bv[j];
  }
  __syncthreads();
  const float* wo = ca_out_w + (size_t)i * Dn * Dn;
  const float* bo = ca_out_b + i * Dn;
  for (int j = t; j < Dn; j += 256) {
    const float* w = wo + (size_t)j * Dn;
    float s0 = 0, s1 = 0, s2 = 0, s3 = 0;
    for (int k = 0; k < Dn; k += 4) {
      s0 += vs[k]*w[k]; s1 += vs[k+1]*w[k+1]; s2 += vs[k+2]*w[k+2]; s3 += vs[k+3]*w[k+3];
    }
    ca_add[((size_t)i * Bn + b) * Dn + j] = s0 + s1 + s2 + s3 + bo[j];
  }
}

// ---------------- embedding: X = tok_emb[ids] + pos_emb ----------------------
__global__ __launch_bounds__(128)
void k_embed(const int* __restrict__ ids, const float* __restrict__ tok,
             const float* __restrict__ pos, float* __restrict__ X,
             u16* __restrict__ Xb) {
  int r = blockIdx.x;
  int l = r & (Ln - 1);
  int id = ids[r];
  int c = threadIdx.x * 4;
  f4 te = *(const f4*)&tok[(size_t)id * Dn + c];
  f4 pe = *(const f4*)&pos[(size_t)l * Dn + c];
  f4 v = te + pe;
  *(f4*)&X[(size_t)r * Dn + c] = v;
  us4 o = { f2bf(v[0]), f2bf(v[1]), f2bf(v[2]), f2bf(v[3]) };
  *(us4*)&Xb[(size_t)r * Dn + c] = o;
}

// ---------------- fused residual add + LayerNorm -----------------------------
template <int CA>
__global__ __launch_bounds__(128)
void k_add_ln(float* __restrict__ X, u16* __restrict__ Xb,
              const float* __restrict__ Y, const float* __restrict__ g,
              const float* __restrict__ be) {
  int r = blockIdx.x, t = threadIdx.x;
  int c = t * 4;
  const float* yrow = CA ? (Y + (size_t)(r >> 7) * Dn) : (Y + (size_t)r * Dn);
  f4 x = *(const f4*)&X[(size_t)r * Dn + c];
  f4 y = *(const f4*)&yrow[c];
  f4 v = x + y;
  float sum = v[0] + v[1] + v[2] + v[3];
  float sq = v[0]*v[0] + v[1]*v[1] + v[2]*v[2] + v[3]*v[3];
  for (int off = 32; off; off >>= 1) {
    sum += __shfl_down(sum, off, 64);
    sq  += __shfl_down(sq,  off, 64);
  }
  __shared__ float red[4];
  int lane = t & 63, w = t >> 6;
  if (!lane) { red[w] = sum; red[2 + w] = sq; }
  __syncthreads();
  sum = red[0] + red[1]; sq = red[2] + red[3];
  float mu = sum * (1.0f / Dn);
  float var = sq * (1.0f / Dn) - mu * mu;
  float rstd = rsqrtf(fmaxf(var, 0.0f) + 1e-5f);
  f4 gg = *(const f4*)&g[c];
  f4 bb = *(const f4*)&be[c];
  f4 o = (v - mu) * rstd * gg + bb;
  *(f4*)&X[(size_t)r * Dn + c] = o;
  us4 ob = { f2bf(o[0]), f2bf(o[1]), f2bf(o[2]), f2bf(o[3]) };
  *(us4*)&Xb[(size_t)r * Dn + c] = ob;
}

// ---------------- causal self-attention (bf16 QKV in), one (b,h)/block -------
__global__ __launch_bounds__(128)
void k_attn(const u16* __restrict__ QKV, u16* __restrict__ Ob) {
  int bh = blockIdx.x;
  int b = bh >> 3, h = bh & 7;
  int t = threadIdx.x;  // q row
  __shared__ float Ks[Ln][HDn];
  __shared__ float Vs[Ln][HDn];
  __shared__ float Ss[Ln][Ln + 1];
  const u16* base = QKV + (size_t)(b * Ln + t) * 1536;
  const u16* krow = base + 512 + h * HDn;
  const u16* vrow = base + 1024 + h * HDn;
  float q[HDn];
  const u16* qrow = base + h * HDn;
  #pragma unroll
  for (int i = 0; i < HDn; i += 8) {
    short8 kv = *(const short8*)&krow[i];
    short8 vv = *(const short8*)&vrow[i];
    short8 qv = *(const short8*)&qrow[i];
    #pragma unroll
    for (int j = 0; j < 8; j++) {
      Ks[t][i + j] = bf2f((u16)kv[j]);
      Vs[t][i + j] = bf2f((u16)vv[j]);
      q[i + j] = bf2f((u16)qv[j]);
    }
  }
  __syncthreads();
  float m = -1e30f;
  for (int k = 0; k <= t; k++) {
    float s0 = 0, s1 = 0, s2 = 0, s3 = 0;
    #pragma unroll
    for (int i = 0; i < HDn; i += 4) {
      s0 += q[i] * Ks[k][i];     s1 += q[i+1] * Ks[k][i+1];
      s2 += q[i+2] * Ks[k][i+2]; s3 += q[i+3] * Ks[k][i+3];
    }
    float s = (s0 + s1 + s2 + s3) * 0.125f;
    Ss[t][k] = s;
    m = fmaxf(m, s);
  }
  float l = 0.0f;
  for (int k = 0; k <= t; k++) {
    float p = __expf(Ss[t][k] - m);
    Ss[t][k] = p;
    l += p;
  }
  float inv = 1.0f / l;
  float o[HDn] = {0};
  for (int k = 0; k <= t; k++) {
    float p = Ss[t][k];
    #pragma unroll
    for (int i = 0; i < HDn; i += 4) {
      o[i]   += p * Vs[k][i];   o[i+1] += p * Vs[k][i+1];
      o[i+2] += p * Vs[k][i+2]; o[i+3] += p * Vs[k][i+3];
    }
  }
  u16* orow = Ob + (size_t)(b * Ln + t) * Dn + h * HDn;
  #pragma unroll
  for (int i = 0; i < HDn; i += 4) {
    us4 v = { f2bf(o[i] * inv), f2bf(o[i+1] * inv),
              f2bf(o[i+2] * inv), f2bf(o[i+3] * inv) };
    *(us4*)&orow[i] = v;
  }
}

// ---------------- bf16 MFMA GEMM: C = A(MxK) * W(NxK)^T + bias ---------------
// 128xBNT tile, BK=32, 4 waves (2x2), global_load_lds width 16, XCD swizzle.
// EPI 0: f32 +bias.  EPI 1: relu(+bias)->bf16.  EPI 2: +bias->bf16.
template <int EPI, int BNT>
__global__ __launch_bounds__(256, 2)
void k_gemm_bt(const u16* __restrict__ A, const u16* __restrict__ Bw,
               const float* __restrict__ bias, void* __restrict__ Cout,
               int gm, int N, int K, int ldc) {
  constexpr int NREP = BNT / 32;          // N-frags per wave
  __shared__ u16 As[128 * 32];
  __shared__ u16 Bs[BNT * 32];
  int nwg = gridDim.x;
  int lin = blockIdx.x;
  // bijective XCD swizzle (all our grids are multiples of 8); bm fastest
  int idx = ((nwg & 7) == 0) ? ((lin & 7) * (nwg >> 3) + (lin >> 3)) : lin;
  int bm = idx % gm;
  int bn = idx / gm;
  int tid = threadIdx.x;
  int lane = tid & 63;
  int wid = tid >> 6;
  int wr = wid >> 1, wc = wid & 1;
  f32x4 acc[4][NREP] = {};

  int c0 = tid, c1 = tid + 256;
  const u16* a0 = A + (size_t)(bm * 128 + (c0 >> 2)) * K + (c0 & 3) * 8;
  const u16* a1 = A + (size_t)(bm * 128 + (c1 >> 2)) * K + (c1 & 3) * 8;
  char* lA0 = (char*)As + c0 * 16;
  char* lA1 = (char*)As + c1 * 16;
  const u16* b0 = Bw + (size_t)(bn * BNT + (c0 >> 2)) * K + (c0 & 3) * 8;
  char* lB0 = (char*)Bs + c0 * 16;
  const u16* b1 = nullptr;
  char* lB1 = nullptr;
  if constexpr (BNT == 128) {
    b1 = Bw + (size_t)(bn * 128 + (c1 >> 2)) * K + (c1 & 3) * 8;
    lB1 = (char*)Bs + c1 * 16;
  }
  int fr = lane & 15, kq = (lane >> 4) * 8;

  for (int k0 = 0; k0 < K; k0 += 32) {
    __syncthreads();
    __builtin_amdgcn_global_load_lds(
        (const __attribute__((address_space(1))) unsigned int*)(a0 + k0),
        (__attribute__((address_space(3))) unsigned int*)lA0, 16, 0, 0);
    __builtin_amdgcn_global_load_lds(
        (const __attribute__((address_space(1))) unsigned int*)(a1 + k0),
        (__attribute__((address_space(3))) unsigned int*)lA1, 16, 0, 0);
    __builtin_amdgcn_global_load_lds(
        (const __attribute__((address_space(1))) unsigned int*)(b0 + k0),
        (__attribute__((address_space(3))) unsigned int*)lB0, 16, 0, 0);
    if constexpr (BNT == 128)
      __builtin_amdgcn_global_load_lds(
          (const __attribute__((address_space(1))) unsigned int*)(b1 + k0),
          (__attribute__((address_space(3))) unsigned int*)lB1, 16, 0, 0);
    __syncthreads();
    short8 av[4], bv[NREP];
    #pragma unroll
    for (int mi = 0; mi < 4; mi++)
      av[mi] = *(const short8*)&As[(wr * 64 + mi * 16 + fr) * 32 + kq];
    #pragma unroll
    for (int nj = 0; nj < NREP; nj++)
      bv[nj] = *(const short8*)&Bs[(wc * (BNT/2) + nj * 16 + fr) * 32 + kq];
    #pragma unroll
    for (int mi = 0; mi < 4; mi++)
      #pragma unroll
      for (int nj = 0; nj < NREP; nj++)
        acc[mi][nj] = __builtin_amdgcn_mfma_f32_16x16x32_bf16(
            av[mi], bv[nj], acc[mi][nj], 0, 0, 0);
  }

  int rbase = bm * 128 + wr * 64 + (lane >> 4) * 4;
  int cbase = bn * BNT + wc * (BNT/2) + fr;
  #pragma unroll
  for (int nj = 0; nj < NREP; nj++) {
    int col = cbase + nj * 16;
    if (BNT == 128 && col >= N) continue;
    float bb = bias[col];
    #pragma unroll
    for (int mi = 0; mi < 4; mi++) {
      int row = rbase + mi * 16;
      #pragma unroll
      for (int r = 0; r < 4; r++) {
        float v = acc[mi][nj][r] + bb;
        if (EPI == 1) {
          v = fmaxf(v, 0.0f);
          ((u16*)Cout)[(size_t)(row + r) * ldc + col] = f2bf(v);
        } else if (EPI == 2) {
          ((u16*)Cout)[(size_t)(row + r) * ldc + col] = f2bf(v);
        } else {
          ((float*)Cout)[(size_t)(row + r) * ldc + col] = v;
        }
      }
    }
  }
}

// =============================================================================
extern "C" void kernel_launch(void* const* d_in, const int* in_sizes, int n_in,
                              void* d_out, int out_size, void* d_ws, size_t ws_size,
                              hipStream_t stream) {
  const float* z        = (const float*)d_in[0];
  const int*   ids      = (const int*)d_in[1];
  const float* tok      = (const float*)d_in[2];
  const float* pos      = (const float*)d_in[3];
  const float* lp_w     = (const float*)d_in[4];
  const float* lp_b     = (const float*)d_in[5];
  const float* lp_g     = (const float*)d_in[6];
  const float* lp_be    = (const float*)d_in[7];
  const float* sa_qkv_w = (const float*)d_in[8];
  const float* sa_qkv_b = (const float*)d_in[9];
  const float* sa_out_w = (const float*)d_in[10];
  const float* sa_out_b = (const float*)d_in[11];
  const float* ca_qkv_w = (const float*)d_in[12];
  const float* ca_qkv_b = (const float*)d_in[13];
  const float* ca_out_w = (const float*)d_in[14];
  const float* ca_out_b = (const float*)d_in[15];
  const float* ln1_g    = (const float*)d_in[16];
  const float* ln1_b    = (const float*)d_in[17];
  const float* ln2_g    = (const float*)d_in[18];
  const float* ln2_b    = (const float*)d_in[19];
  const float* ln3_g    = (const float*)d_in[20];
  const float* ln3_b    = (const float*)d_in[21];
  const float* ff1_w    = (const float*)d_in[22];
  const float* ff1_b    = (const float*)d_in[23];
  const float* ff2_w    = (const float*)d_in[24];
  const float* ff2_b    = (const float*)d_in[25];
  const float* op_w     = (const float*)d_in[26];
  const float* op_b     = (const float*)d_in[27];

  char* ws = (char*)d_ws;
  float* X      = (float*)(ws + 0);           // 4096x512 f32
  float* Y      = (float*)(ws + 8388608);     // 4096x512 f32
  u16*   QKVb   = (u16*)(ws + 16777216);      // 4096x1536 bf16
  u16*   Xb     = (u16*)(ws + 29360128);      // 4096x512 bf16
  u16*   Ob     = (u16*)(ws + 33554432);      // 4096x512 bf16
  u16*   H1b    = (u16*)(ws + 37748736);      // 4096x2048 bf16
  float* mem    = (float*)(ws + 54525952);    // 32x512 f32
  float* ca_add = (float*)(ws + 54657024);    // 4x32x512 f32
  u16*   Wa     = (u16*)(ws + 55050240);      // weight arena bf16

  u16* Wqkv = Wa;                              // 4 x 1536x512
  u16* Wout = Wa + 3145728;                    // 4 x 512x512
  u16* Wff1 = Wa + 4194304;                    // 4 x 2048x512
  u16* Wff2 = Wa + 8388608;                    // 4 x 512x2048
  u16* Wop  = Wa + 12582912;                   // 50304x512 (zero-padded tail)

  auto cvt = [&](const float* src, u16* dst, int n, int npad) {
    int n4 = n / 4, n4p = npad / 4;
    int blocks = (n4p + 255) / 256;
    if (blocks > 2048) blocks = 2048;
    k_cvt_bf16<<<blocks, 256, 0, stream>>>((const f4*)src, (us4*)dst, n4, n4p);
  };

  // upfront: small pre-kernels + ALL weight conversions (contiguous across layers)
  k_latent_mem<<<Bn, 256, 0, stream>>>(z, lp_w, lp_b, lp_g, lp_be, mem);
  k_ca<<<4 * Bn, 256, 0, stream>>>(mem, ca_qkv_w, ca_qkv_b, ca_out_w, ca_out_b, ca_add);
  k_embed<<<Bn * Ln, 128, 0, stream>>>(ids, tok, pos, X, Xb);
  cvt(sa_qkv_w, Wqkv, 4 * 1536 * Dn, 4 * 1536 * Dn);
  cvt(sa_out_w, Wout, 4 * Dn * Dn, 4 * Dn * Dn);
  cvt(ff1_w,    Wff1, 4 * DFn * Dn, 4 * DFn * Dn);
  cvt(ff2_w,    Wff2, 4 * Dn * DFn, 4 * Dn * DFn);
  cvt(op_w,     Wop,  Vn * Dn, VPAD * Dn);

  const int M = Bn * Ln;  // 4096
  for (int i = 0; i < 4; i++) {
    k_gemm_bt<2, 128><<<32 * 12, 256, 0, stream>>>(
        Xb, Wqkv + (size_t)i * 1536 * Dn, sa_qkv_b + i * 1536, QKVb, 32, 1536, Dn, 1536);
    k_attn<<<Bn * Hn, 128, 0, stream>>>(QKVb, Ob);
    k_gemm_bt<0, 64><<<32 * 8, 256, 0, stream>>>(
        Ob, Wout + (size_t)i * Dn * Dn, sa_out_b + i * Dn, Y, 32, Dn, Dn, Dn);
    k_add_ln<0><<<M, 128, 0, stream>>>(X, Xb, Y, ln1_g + i * Dn, ln1_b + i * Dn);
    k_add_ln<1><<<M, 128, 0, stream>>>(X, Xb, ca_add + (size_t)i * Bn * Dn,
                                       ln2_g + i * Dn, ln2_b + i * Dn);
    k_gemm_bt<1, 128><<<32 * 16, 256, 0, stream>>>(
        Xb, Wff1 + (size_t)i * DFn * Dn, ff1_b + i * DFn, H1b, 32, DFn, Dn, DFn);
    k_gemm_bt<0, 64><<<32 * 8, 256, 0, stream>>>(
        H1b, Wff2 + (size_t)i * Dn * DFn, ff2_b + i * Dn, Y, 32, Dn, DFn, Dn);
    k_add_ln<0><<<M, 128, 0, stream>>>(X, Xb, Y, ln3_g + i * Dn, ln3_b + i * Dn);
  }

  // final vocab projection -> d_out (f32)
  k_gemm_bt<0, 128><<<32 * 393, 256, 0, stream>>>(
      Xb, Wop, op_b, (float*)d_out, 32, Vn, Dn, Vn);
}

// Round 4
// 1225.104 us; speedup vs baseline: 1.1718x; 1.1718x over previous
//
#include <hip/hip_runtime.h>
#include <math.h>

typedef __attribute__((ext_vector_type(8))) short short8;
typedef __attribute__((ext_vector_type(4))) float f32x4;
typedef __attribute__((ext_vector_type(4))) float f4;
typedef __attribute__((ext_vector_type(4))) unsigned short us4;
typedef unsigned short u16;

#define Bn 32
#define Ln 128
#define Dn 512
#define LATn 256
#define Vn 50257
#define VPAD 50304
#define DFn 2048
#define Hn 8
#define HDn 64

#define GLD(src, dst) __builtin_amdgcn_global_load_lds( \
    (const __attribute__((address_space(1))) unsigned int*)(src), \
    (__attribute__((address_space(3))) unsigned int*)(dst), 16, 0, 0)

__device__ __forceinline__ u16 f2bf(float f) {
  union { float f; unsigned u; } v; v.f = f;
  unsigned r = 0x7FFFu + ((v.u >> 16) & 1u);
  return (u16)((v.u + r) >> 16);
}
__device__ __forceinline__ float bf2f(u16 u) {
  union { unsigned u; float f; } v; v.u = ((unsigned)u) << 16;
  return v.f;
}

// ---------------- f32 -> bf16 conversion (weights), zero-padded tail ---------
__global__ void k_cvt_bf16(const f4* __restrict__ in, us4* __restrict__ out,
                           int n4, int n4pad) {
  int i = blockIdx.x * blockDim.x + threadIdx.x;
  int stride = gridDim.x * blockDim.x;
  for (; i < n4pad; i += stride) {
    us4 o;
    if (i < n4) {
      f4 v = in[i];
      o[0] = f2bf(v[0]); o[1] = f2bf(v[1]); o[2] = f2bf(v[2]); o[3] = f2bf(v[3]);
    } else {
      o[0] = 0; o[1] = 0; o[2] = 0; o[3] = 0;
    }
    out[i] = o;
  }
}

// ---------------- latent_proj: mem = LN(GELU(z @ lp_w.T + lp_b)) -------------
__global__ __launch_bounds__(256)
void k_latent_mem(const float* __restrict__ z, const float* __restrict__ lp_w,
                  const float* __restrict__ lp_b, const float* __restrict__ g,
                  const float* __restrict__ be, float* __restrict__ mem) {
  __shared__ float zs[LATn];
  __shared__ float red[16];
  int b = blockIdx.x, t = threadIdx.x;
  zs[t] = z[b * LATn + t];
  __syncthreads();
  float h[2];
  #pragma unroll
  for (int j = 0; j < 2; j++) {
    int oj = t + j * 256;
    const float* w = lp_w + (size_t)oj * LATn;
    float s0 = 0, s1 = 0, s2 = 0, s3 = 0;
    for (int k = 0; k < LATn; k += 4) {
      s0 += zs[k] * w[k]; s1 += zs[k+1] * w[k+1];
      s2 += zs[k+2] * w[k+2]; s3 += zs[k+3] * w[k+3];
    }
    float x = s0 + s1 + s2 + s3 + lp_b[oj];
    h[j] = 0.5f * x * (1.0f + erff(x * 0.70710678118654752f));
  }
  float sum = h[0] + h[1], sq = h[0]*h[0] + h[1]*h[1];
  for (int off = 32; off; off >>= 1) {
    sum += __shfl_down(sum, off, 64);
    sq  += __shfl_down(sq,  off, 64);
  }
  int lane = t & 63, wid = t >> 6;
  if (!lane) { red[wid] = sum; red[8 + wid] = sq; }
  __syncthreads();
  float ts = red[0] + red[1] + red[2] + red[3];
  float tq = red[8] + red[9] + red[10] + red[11];
  float mu = ts * (1.0f / Dn);
  float var = tq * (1.0f / Dn) - mu * mu;
  float rstd = rsqrtf(fmaxf(var, 0.0f) + 1e-5f);
  #pragma unroll
  for (int j = 0; j < 2; j++) {
    int oj = t + j * 256;
    mem[b * Dn + oj] = (h[j] - mu) * rstd * g[oj] + be[oj];
  }
}

// ------------- cross-attention precompute (Lk=1 => softmax==1 => o = v) ------
__global__ __launch_bounds__(256)
void k_ca(const float* __restrict__ mem, const float* __restrict__ ca_qkv_w,
          const float* __restrict__ ca_qkv_b, const float* __restrict__ ca_out_w,
          const float* __restrict__ ca_out_b, float* __restrict__ ca_add) {
  int blk = blockIdx.x;
  int i = blk >> 5, b = blk & 31, t = threadIdx.x;
  __shared__ float ms[Dn];
  __shared__ float vs[Dn];
  ms[t] = mem[b * Dn + t];
  ms[t + 256] = mem[b * Dn + t + 256];
  __syncthreads();
  const float* wv = ca_qkv_w + ((size_t)i * 1536 + 1024) * Dn;
  const float* bv = ca_qkv_b + i * 1536 + 1024;
  for (int j = t; j < Dn; j += 256) {
    const float* w = wv + (size_t)j * Dn;
    float s0 = 0, s1 = 0, s2 = 0, s3 = 0;
    for (int k = 0; k < Dn; k += 4) {
      s0 += ms[k]*w[k]; s1 += ms[k+1]*w[k+1]; s2 += ms[k+2]*w[k+2]; s3 += ms[k+3]*w[k+3];
    }
    vs[j] = s0 + s1 + s2 + s3 + bv[j];
  }
  __syncthreads();
  const float* wo = ca_out_w + (size_t)i * Dn * Dn;
  const float* bo = ca_out_b + i * Dn;
  for (int j = t; j < Dn; j += 256) {
    const float* w = wo + (size_t)j * Dn;
    float s0 = 0, s1 = 0, s2 = 0, s3 = 0;
    for (int k = 0; k < Dn; k += 4) {
      s0 += vs[k]*w[k]; s1 += vs[k+1]*w[k+1]; s2 += vs[k+2]*w[k+2]; s3 += vs[k+3]*w[k+3];
    }
    ca_add[((size_t)i * Bn + b) * Dn + j] = s0 + s1 + s2 + s3 + bo[j];
  }
}

// ---------------- embedding: X = tok_emb[ids] + pos_emb ----------------------
__global__ __launch_bounds__(128)
void k_embed(const int* __restrict__ ids, const float* __restrict__ tok,
             const float* __restrict__ pos, float* __restrict__ X,
             u16* __restrict__ Xb) {
  int r = blockIdx.x;
  int l = r & (Ln - 1);
  int id = ids[r];
  int c = threadIdx.x * 4;
  f4 te = *(const f4*)&tok[(size_t)id * Dn + c];
  f4 pe = *(const f4*)&pos[(size_t)l * Dn + c];
  f4 v = te + pe;
  *(f4*)&X[(size_t)r * Dn + c] = v;
  us4 o = { f2bf(v[0]), f2bf(v[1]), f2bf(v[2]), f2bf(v[3]) };
  *(us4*)&Xb[(size_t)r * Dn + c] = o;
}

// ---------------- fused residual add + LayerNorm (single) --------------------
__global__ __launch_bounds__(128)
void k_add_ln(float* __restrict__ X, u16* __restrict__ Xb,
              const float* __restrict__ Y, const float* __restrict__ g,
              const float* __restrict__ be) {
  int r = blockIdx.x, t = threadIdx.x;
  int c = t * 4;
  f4 x = *(const f4*)&X[(size_t)r * Dn + c];
  f4 y = *(const f4*)&Y[(size_t)r * Dn + c];
  f4 v = x + y;
  float sum = v[0] + v[1] + v[2] + v[3];
  float sq = v[0]*v[0] + v[1]*v[1] + v[2]*v[2] + v[3]*v[3];
  for (int off = 32; off; off >>= 1) {
    sum += __shfl_down(sum, off, 64);
    sq  += __shfl_down(sq,  off, 64);
  }
  __shared__ float red[4];
  int lane = t & 63, w = t >> 6;
  if (!lane) { red[w] = sum; red[2 + w] = sq; }
  __syncthreads();
  sum = red[0] + red[1]; sq = red[2] + red[3];
  float mu = sum * (1.0f / Dn);
  float var = sq * (1.0f / Dn) - mu * mu;
  float rstd = rsqrtf(fmaxf(var, 0.0f) + 1e-5f);
  f4 gg = *(const f4*)&g[c];
  f4 bb = *(const f4*)&be[c];
  f4 o = (v - mu) * rstd * gg + bb;
  *(f4*)&X[(size_t)r * Dn + c] = o;
  us4 ob = { f2bf(o[0]), f2bf(o[1]), f2bf(o[2]), f2bf(o[3]) };
  *(us4*)&Xb[(size_t)r * Dn + c] = ob;
}

// ---------------- fused LN1(X+Y) then LN2(. + CA) ----------------------------
__global__ __launch_bounds__(128)
void k_add_ln12(float* __restrict__ X, u16* __restrict__ Xb,
                const float* __restrict__ Y, const float* __restrict__ CA,
                const float* __restrict__ g1, const float* __restrict__ b1,
                const float* __restrict__ g2, const float* __restrict__ b2) {
  int r = blockIdx.x, t = threadIdx.x;
  int c = t * 4;
  __shared__ float red[8];
  int lane = t & 63, w = t >> 6;
  f4 x = *(const f4*)&X[(size_t)r * Dn + c];
  f4 y = *(const f4*)&Y[(size_t)r * Dn + c];
  f4 v = x + y;
  float sum = v[0] + v[1] + v[2] + v[3];
  float sq = v[0]*v[0] + v[1]*v[1] + v[2]*v[2] + v[3]*v[3];
  for (int off = 32; off; off >>= 1) {
    sum += __shfl_down(sum, off, 64);
    sq  += __shfl_down(sq,  off, 64);
  }
  if (!lane) { red[w] = sum; red[2 + w] = sq; }
  __syncthreads();
  sum = red[0] + red[1]; sq = red[2] + red[3];
  float mu = sum * (1.0f / Dn);
  float var = sq * (1.0f / Dn) - mu * mu;
  float rstd = rsqrtf(fmaxf(var, 0.0f) + 1e-5f);
  f4 g1v = *(const f4*)&g1[c];
  f4 b1v = *(const f4*)&b1[c];
  f4 o1 = (v - mu) * rstd * g1v + b1v;
  f4 ca = *(const f4*)&CA[(size_t)(r >> 7) * Dn + c];
  f4 v2 = o1 + ca;
  float sum2 = v2[0] + v2[1] + v2[2] + v2[3];
  float sq2 = v2[0]*v2[0] + v2[1]*v2[1] + v2[2]*v2[2] + v2[3]*v2[3];
  for (int off = 32; off; off >>= 1) {
    sum2 += __shfl_down(sum2, off, 64);
    sq2  += __shfl_down(sq2,  off, 64);
  }
  if (!lane) { red[4 + w] = sum2; red[6 + w] = sq2; }
  __syncthreads();
  sum2 = red[4] + red[5]; sq2 = red[6] + red[7];
  float mu2 = sum2 * (1.0f / Dn);
  float var2 = sq2 * (1.0f / Dn) - mu2 * mu2;
  float rstd2 = rsqrtf(fmaxf(var2, 0.0f) + 1e-5f);
  f4 g2v = *(const f4*)&g2[c];
  f4 b2v = *(const f4*)&b2[c];
  f4 o2 = (v2 - mu2) * rstd2 * g2v + b2v;
  *(f4*)&X[(size_t)r * Dn + c] = o2;
  us4 ob = { f2bf(o2[0]), f2bf(o2[1]), f2bf(o2[2]), f2bf(o2[3]) };
  *(us4*)&Xb[(size_t)r * Dn + c] = ob;
}

// ---------------- causal self-attention (bf16 QKV in), one (b,h)/block -------
__global__ __launch_bounds__(128)
void k_attn(const u16* __restrict__ QKV, u16* __restrict__ Ob) {
  int bh = blockIdx.x;
  int b = bh >> 3, h = bh & 7;
  int t = threadIdx.x;  // q row
  __shared__ float Ks[Ln][HDn];
  __shared__ float Vs[Ln][HDn];
  __shared__ float Ss[Ln][Ln + 1];
  const u16* base = QKV + (size_t)(b * Ln + t) * 1536;
  const u16* krow = base + 512 + h * HDn;
  const u16* vrow = base + 1024 + h * HDn;
  float q[HDn];
  const u16* qrow = base + h * HDn;
  #pragma unroll
  for (int i = 0; i < HDn; i += 8) {
    short8 kv = *(const short8*)&krow[i];
    short8 vv = *(const short8*)&vrow[i];
    short8 qv = *(const short8*)&qrow[i];
    #pragma unroll
    for (int j = 0; j < 8; j++) {
      Ks[t][i + j] = bf2f((u16)kv[j]);
      Vs[t][i + j] = bf2f((u16)vv[j]);
      q[i + j] = bf2f((u16)qv[j]);
    }
  }
  __syncthreads();
  float m = -1e30f;
  for (int k = 0; k <= t; k++) {
    float s0 = 0, s1 = 0, s2 = 0, s3 = 0;
    #pragma unroll
    for (int i = 0; i < HDn; i += 4) {
      s0 += q[i] * Ks[k][i];     s1 += q[i+1] * Ks[k][i+1];
      s2 += q[i+2] * Ks[k][i+2]; s3 += q[i+3] * Ks[k][i+3];
    }
    float s = (s0 + s1 + s2 + s3) * 0.125f;
    Ss[t][k] = s;
    m = fmaxf(m, s);
  }
  float l = 0.0f;
  for (int k = 0; k <= t; k++) {
    float p = __expf(Ss[t][k] - m);
    Ss[t][k] = p;
    l += p;
  }
  float inv = 1.0f / l;
  float o[HDn] = {0};
  for (int k = 0; k <= t; k++) {
    float p = Ss[t][k];
    #pragma unroll
    for (int i = 0; i < HDn; i += 4) {
      o[i]   += p * Vs[k][i];   o[i+1] += p * Vs[k][i+1];
      o[i+2] += p * Vs[k][i+2]; o[i+3] += p * Vs[k][i+3];
    }
  }
  u16* orow = Ob + (size_t)(b * Ln + t) * Dn + h * HDn;
  #pragma unroll
  for (int i = 0; i < HDn; i += 4) {
    us4 v = { f2bf(o[i] * inv), f2bf(o[i+1] * inv),
              f2bf(o[i+2] * inv), f2bf(o[i+3] * inv) };
    *(us4*)&orow[i] = v;
  }
}

// ---------------- bf16 MFMA GEMM: C = A(MxK) * W(NxK)^T + bias ---------------
// 128xBNT tile, BK=32, 4 waves (2x2). T3-minimum 2-phase double-buffer:
// one barrier/iter; stage(it+1) issued before compute; vmcnt(0)+lgkmcnt(0)
// drained AFTER compute (latency hidden under MFMA). LDS-transpose epilogue.
// EPI 0: f32 +bias (col<N masked).  EPI 1: relu(+bias)->bf16.  EPI 2: +bias->bf16.
template <int EPI, int BNT>
__global__ __launch_bounds__(256, 2)
void k_gemm_bt(const u16* __restrict__ A, const u16* __restrict__ Bw,
               const float* __restrict__ bias, void* __restrict__ Cout,
               int gm, int N, int K, int ldc) {
  constexpr int NREP = BNT / 32;
  __shared__ u16 As[2][128 * 32];
  __shared__ u16 Bs[2][BNT * 32];
  __shared__ float Ts[2][16][BNT + 4];
  int lin = blockIdx.x;
  int bm = lin % gm, bn = lin / gm;     // bm fastest
  int tid = threadIdx.x, lane = tid & 63, wid = tid >> 6;
  int wr = wid >> 1, wc = wid & 1;
  f32x4 acc[4][NREP] = {};

  int c0 = tid, c1 = tid + 256;
  const u16* a0 = A + (size_t)(bm * 128 + (c0 >> 2)) * K + (c0 & 3) * 8;
  const u16* a1 = A + (size_t)(bm * 128 + (c1 >> 2)) * K + (c1 & 3) * 8;
  const u16* b0 = Bw + (size_t)(bn * BNT + (c0 >> 2)) * K + (c0 & 3) * 8;
  const u16* b1 = (BNT == 128)
      ? Bw + (size_t)(bn * 128 + (c1 >> 2)) * K + (c1 & 3) * 8 : b0;
  int fr = lane & 15, kq = (lane >> 4) * 8;
  int nt = K >> 5;

  auto stage = [&](int it) {
    int buf = it & 1;
    GLD(a0 + it * 32, (char*)&As[buf][0] + c0 * 16);
    GLD(a1 + it * 32, (char*)&As[buf][0] + c1 * 16);
    GLD(b0 + it * 32, (char*)&Bs[buf][0] + c0 * 16);
    if constexpr (BNT == 128)
      GLD(b1 + it * 32, (char*)&Bs[buf][0] + c1 * 16);
  };

  // prologue: fill buf0, drain, barrier
  stage(0);
  asm volatile("s_waitcnt vmcnt(0)" ::: "memory");
  __builtin_amdgcn_sched_barrier(0);
  __builtin_amdgcn_s_barrier();
  __builtin_amdgcn_sched_barrier(0);

  for (int it = 0; it < nt; ++it) {
    int cur = it & 1;
    if (it + 1 < nt) stage(it + 1);       // writes buf cur^1
    short8 av[4], bv[NREP];
    #pragma unroll
    for (int mi = 0; mi < 4; mi++)
      av[mi] = *(const short8*)&As[cur][(wr * 64 + mi * 16 + fr) * 32 + kq];
    #pragma unroll
    for (int nj = 0; nj < NREP; nj++)
      bv[nj] = *(const short8*)&Bs[cur][(wc * (BNT / 2) + nj * 16 + fr) * 32 + kq];
    #pragma unroll
    for (int mi = 0; mi < 4; mi++)
      #pragma unroll
      for (int nj = 0; nj < NREP; nj++)
        acc[mi][nj] = __builtin_amdgcn_mfma_f32_16x16x32_bf16(
            av[mi], bv[nj], acc[mi][nj], 0, 0, 0);
    // drain my ds_reads (buf cur) and my staging writes (buf cur^1), then sync
    asm volatile("s_waitcnt vmcnt(0) lgkmcnt(0)" ::: "memory");
    __builtin_amdgcn_sched_barrier(0);
    __builtin_amdgcn_s_barrier();
    __builtin_amdgcn_sched_barrier(0);
  }

  // ---- epilogue: LDS transpose -> coalesced stores ----
  float bb[NREP];
  #pragma unroll
  for (int nj = 0; nj < NREP; nj++) {
    int cg = bn * BNT + wc * (BNT / 2) + nj * 16 + fr;
    bb[nj] = (cg < N) ? bias[cg] : 0.0f;
  }
  int rl0 = (lane >> 4) * 4;
  #pragma unroll
  for (int mi = 0; mi < 4; mi++) {
    #pragma unroll
    for (int nj = 0; nj < NREP; nj++) {
      int colL = wc * (BNT / 2) + nj * 16 + fr;
      #pragma unroll
      for (int r = 0; r < 4; r++)
        Ts[wr][rl0 + r][colL] = acc[mi][nj][r] + bb[nj];
    }
    __syncthreads();
    constexpr int ITERS = (32 * BNT) / 256;
    #pragma unroll
    for (int i = 0; i < ITERS; i++) {
      int flat = i * 256 + tid;
      int rowf = flat / BNT, col = flat % BNT;
      float v = Ts[rowf >> 4][rowf & 15][col];
      int row_g = bm * 128 + (rowf >> 4) * 64 + mi * 16 + (rowf & 15);
      int col_g = bn * BNT + col;
      size_t off = (size_t)row_g * ldc + col_g;
      if (EPI == 0) {
        if (col_g < N) ((float*)Cout)[off] = v;
      } else if (EPI == 1) {
        ((u16*)Cout)[off] = f2bf(fmaxf(v, 0.0f));
      } else {
        ((u16*)Cout)[off] = f2bf(v);
      }
    }
    if (mi < 3) __syncthreads();
  }
}

// =============================================================================
extern "C" void kernel_launch(void* const* d_in, const int* in_sizes, int n_in,
                              void* d_out, int out_size, void* d_ws, size_t ws_size,
                              hipStream_t stream) {
  const float* z        = (const float*)d_in[0];
  const int*   ids      = (const int*)d_in[1];
  const float* tok      = (const float*)d_in[2];
  const float* pos      = (const float*)d_in[3];
  const float* lp_w     = (const float*)d_in[4];
  const float* lp_b     = (const float*)d_in[5];
  const float* lp_g     = (const float*)d_in[6];
  const float* lp_be    = (const float*)d_in[7];
  const float* sa_qkv_w = (const float*)d_in[8];
  const float* sa_qkv_b = (const float*)d_in[9];
  const float* sa_out_w = (const float*)d_in[10];
  const float* sa_out_b = (const float*)d_in[11];
  const float* ca_qkv_w = (const float*)d_in[12];
  const float* ca_qkv_b = (const float*)d_in[13];
  const float* ca_out_w = (const float*)d_in[14];
  const float* ca_out_b = (const float*)d_in[15];
  const float* ln1_g    = (const float*)d_in[16];
  const float* ln1_b    = (const float*)d_in[17];
  const float* ln2_g    = (const float*)d_in[18];
  const float* ln2_b    = (const float*)d_in[19];
  const float* ln3_g    = (const float*)d_in[20];
  const float* ln3_b    = (const float*)d_in[21];
  const float* ff1_w    = (const float*)d_in[22];
  const float* ff1_b    = (const float*)d_in[23];
  const float* ff2_w    = (const float*)d_in[24];
  const float* ff2_b    = (const float*)d_in[25];
  const float* op_w     = (const float*)d_in[26];
  const float* op_b     = (const float*)d_in[27];

  char* ws = (char*)d_ws;
  float* X      = (float*)(ws + 0);           // 4096x512 f32
  float* Y      = (float*)(ws + 8388608);     // 4096x512 f32
  u16*   QKVb   = (u16*)(ws + 16777216);      // 4096x1536 bf16
  u16*   Xb     = (u16*)(ws + 29360128);      // 4096x512 bf16
  u16*   Ob     = (u16*)(ws + 33554432);      // 4096x512 bf16
  u16*   H1b    = (u16*)(ws + 37748736);      // 4096x2048 bf16
  float* mem    = (float*)(ws + 54525952);    // 32x512 f32
  float* ca_add = (float*)(ws + 54657024);    // 4x32x512 f32
  u16*   Wa     = (u16*)(ws + 55050240);      // weight arena bf16

  u16* Wqkv = Wa;                              // 4 x 1536x512
  u16* Wout = Wa + 3145728;                    // 4 x 512x512
  u16* Wff1 = Wa + 4194304;                    // 4 x 2048x512
  u16* Wff2 = Wa + 8388608;                    // 4 x 512x2048
  u16* Wop  = Wa + 12582912;                   // 50304x512 (zero-padded tail)

  auto cvt = [&](const float* src, u16* dst, int n, int npad) {
    int n4 = n / 4, n4p = npad / 4;
    int blocks = (n4p + 255) / 256;
    if (blocks > 2048) blocks = 2048;
    k_cvt_bf16<<<blocks, 256, 0, stream>>>((const f4*)src, (us4*)dst, n4, n4p);
  };

  k_latent_mem<<<Bn, 256, 0, stream>>>(z, lp_w, lp_b, lp_g, lp_be, mem);
  k_ca<<<4 * Bn, 256, 0, stream>>>(mem, ca_qkv_w, ca_qkv_b, ca_out_w, ca_out_b, ca_add);
  k_embed<<<Bn * Ln, 128, 0, stream>>>(ids, tok, pos, X, Xb);
  cvt(sa_qkv_w, Wqkv, 4 * 1536 * Dn, 4 * 1536 * Dn);
  cvt(sa_out_w, Wout, 4 * Dn * Dn, 4 * Dn * Dn);
  cvt(ff1_w,    Wff1, 4 * DFn * Dn, 4 * DFn * Dn);
  cvt(ff2_w,    Wff2, 4 * Dn * DFn, 4 * Dn * DFn);
  cvt(op_w,     Wop,  Vn * Dn, VPAD * Dn);

  const int M = Bn * Ln;  // 4096
  for (int i = 0; i < 4; i++) {
    k_gemm_bt<2, 128><<<32 * 12, 256, 0, stream>>>(
        Xb, Wqkv + (size_t)i * 1536 * Dn, sa_qkv_b + i * 1536, QKVb, 32, 1536, Dn, 1536);
    k_attn<<<Bn * Hn, 128, 0, stream>>>(QKVb, Ob);
    k_gemm_bt<0, 64><<<32 * 8, 256, 0, stream>>>(
        Ob, Wout + (size_t)i * Dn * Dn, sa_out_b + i * Dn, Y, 32, Dn, Dn, Dn);
    k_add_ln12<<<M, 128, 0, stream>>>(X, Xb, Y, ca_add + (size_t)i * Bn * Dn,
                                      ln1_g + i * Dn, ln1_b + i * Dn,
                                      ln2_g + i * Dn, ln2_b + i * Dn);
    k_gemm_bt<1, 128><<<32 * 16, 256, 0, stream>>>(
        Xb, Wff1 + (size_t)i * DFn * Dn, ff1_b + i * DFn, H1b, 32, DFn, Dn, DFn);
    k_gemm_bt<0, 64><<<32 * 8, 256, 0, stream>>>(
        H1b, Wff2 + (size_t)i * Dn * DFn, ff2_b + i * Dn, Y, 32, Dn, DFn, Dn);
    k_add_ln<<<M, 128, 0, stream>>>(X, Xb, Y, ln3_g + i * Dn, ln3_b + i * Dn);
  }

  // final vocab projection -> d_out (f32)
  k_gemm_bt<0, 128><<<32 * 393, 256, 0, stream>>>(
      Xb, Wop, op_b, (float*)d_out, 32, Vn, Dn, Vn);
}

// Round 5
// 1160.293 us; speedup vs baseline: 1.2373x; 1.0559x over previous
//
#include <hip/hip_runtime.h>
#include <math.h>

typedef __attribute__((ext_vector_type(8))) short short8;
typedef __attribute__((ext_vector_type(4))) float f32x4;
typedef __attribute__((ext_vector_type(4))) float f4;
typedef __attribute__((ext_vector_type(4))) unsigned short us4;
typedef unsigned short u16;

#define Bn 32
#define Ln 128
#define Dn 512
#define LATn 256
#define Vn 50257
#define VPAD 50304
#define DFn 2048
#define Hn 8
#define HDn 64

#define GLD(src, dst) __builtin_amdgcn_global_load_lds( \
    (const __attribute__((address_space(1))) unsigned int*)(src), \
    (__attribute__((address_space(3))) unsigned int*)(dst), 16, 0, 0)

__device__ __forceinline__ u16 f2bf(float f) {
  union { float f; unsigned u; } v; v.f = f;
  unsigned r = 0x7FFFu + ((v.u >> 16) & 1u);
  return (u16)((v.u + r) >> 16);
}
__device__ __forceinline__ float bf2f(u16 u) {
  union { unsigned u; float f; } v; v.u = ((unsigned)u) << 16;
  return v.f;
}

// ---------------- f32 -> bf16 conversion (weights), zero-padded tail ---------
__global__ void k_cvt_bf16(const f4* __restrict__ in, us4* __restrict__ out,
                           int n4, int n4pad) {
  int i = blockIdx.x * blockDim.x + threadIdx.x;
  int stride = gridDim.x * blockDim.x;
  for (; i < n4pad; i += stride) {
    us4 o;
    if (i < n4) {
      f4 v = in[i];
      o[0] = f2bf(v[0]); o[1] = f2bf(v[1]); o[2] = f2bf(v[2]); o[3] = f2bf(v[3]);
    } else {
      o[0] = 0; o[1] = 0; o[2] = 0; o[3] = 0;
    }
    out[i] = o;
  }
}

// ---------------- latent_proj: mem = LN(GELU(z @ lp_w.T + lp_b)) -------------
__global__ __launch_bounds__(256)
void k_latent_mem(const float* __restrict__ z, const float* __restrict__ lp_w,
                  const float* __restrict__ lp_b, const float* __restrict__ g,
                  const float* __restrict__ be, float* __restrict__ mem) {
  __shared__ float zs[LATn];
  __shared__ float red[16];
  int b = blockIdx.x, t = threadIdx.x;
  zs[t] = z[b * LATn + t];
  __syncthreads();
  float h[2];
  #pragma unroll
  for (int j = 0; j < 2; j++) {
    int oj = t + j * 256;
    const float* w = lp_w + (size_t)oj * LATn;
    float s0 = 0, s1 = 0, s2 = 0, s3 = 0;
    for (int k = 0; k < LATn; k += 4) {
      s0 += zs[k] * w[k]; s1 += zs[k+1] * w[k+1];
      s2 += zs[k+2] * w[k+2]; s3 += zs[k+3] * w[k+3];
    }
    float x = s0 + s1 + s2 + s3 + lp_b[oj];
    h[j] = 0.5f * x * (1.0f + erff(x * 0.70710678118654752f));
  }
  float sum = h[0] + h[1], sq = h[0]*h[0] + h[1]*h[1];
  for (int off = 32; off; off >>= 1) {
    sum += __shfl_down(sum, off, 64);
    sq  += __shfl_down(sq,  off, 64);
  }
  int lane = t & 63, wid = t >> 6;
  if (!lane) { red[wid] = sum; red[8 + wid] = sq; }
  __syncthreads();
  float ts = red[0] + red[1] + red[2] + red[3];
  float tq = red[8] + red[9] + red[10] + red[11];
  float mu = ts * (1.0f / Dn);
  float var = tq * (1.0f / Dn) - mu * mu;
  float rstd = rsqrtf(fmaxf(var, 0.0f) + 1e-5f);
  #pragma unroll
  for (int j = 0; j < 2; j++) {
    int oj = t + j * 256;
    mem[b * Dn + oj] = (h[j] - mu) * rstd * g[oj] + be[oj];
  }
}

// ------------- cross-attention precompute (Lk=1 => softmax==1 => o = v) ------
__global__ __launch_bounds__(256)
void k_ca(const float* __restrict__ mem, const float* __restrict__ ca_qkv_w,
          const float* __restrict__ ca_qkv_b, const float* __restrict__ ca_out_w,
          const float* __restrict__ ca_out_b, float* __restrict__ ca_add) {
  int blk = blockIdx.x;
  int i = blk >> 5, b = blk & 31, t = threadIdx.x;
  __shared__ float ms[Dn];
  __shared__ float vs[Dn];
  ms[t] = mem[b * Dn + t];
  ms[t + 256] = mem[b * Dn + t + 256];
  __syncthreads();
  const float* wv = ca_qkv_w + ((size_t)i * 1536 + 1024) * Dn;
  const float* bv = ca_qkv_b + i * 1536 + 1024;
  for (int j = t; j < Dn; j += 256) {
    const float* w = wv + (size_t)j * Dn;
    float s0 = 0, s1 = 0, s2 = 0, s3 = 0;
    for (int k = 0; k < Dn; k += 4) {
      s0 += ms[k]*w[k]; s1 += ms[k+1]*w[k+1]; s2 += ms[k+2]*w[k+2]; s3 += ms[k+3]*w[k+3];
    }
    vs[j] = s0 + s1 + s2 + s3 + bv[j];
  }
  __syncthreads();
  const float* wo = ca_out_w + (size_t)i * Dn * Dn;
  const float* bo = ca_out_b + i * Dn;
  for (int j = t; j < Dn; j += 256) {
    const float* w = wo + (size_t)j * Dn;
    float s0 = 0, s1 = 0, s2 = 0, s3 = 0;
    for (int k = 0; k < Dn; k += 4) {
      s0 += vs[k]*w[k]; s1 += vs[k+1]*w[k+1]; s2 += vs[k+2]*w[k+2]; s3 += vs[k+3]*w[k+3];
    }
    ca_add[((size_t)i * Bn + b) * Dn + j] = s0 + s1 + s2 + s3 + bo[j];
  }
}

// ---------------- embedding: X = tok_emb[ids] + pos_emb ----------------------
__global__ __launch_bounds__(128)
void k_embed(const int* __restrict__ ids, const float* __restrict__ tok,
             const float* __restrict__ pos, float* __restrict__ X,
             u16* __restrict__ Xb) {
  int r = blockIdx.x;
  int l = r & (Ln - 1);
  int id = ids[r];
  int c = threadIdx.x * 4;
  f4 te = *(const f4*)&tok[(size_t)id * Dn + c];
  f4 pe = *(const f4*)&pos[(size_t)l * Dn + c];
  f4 v = te + pe;
  *(f4*)&X[(size_t)r * Dn + c] = v;
  us4 o = { f2bf(v[0]), f2bf(v[1]), f2bf(v[2]), f2bf(v[3]) };
  *(us4*)&Xb[(size_t)r * Dn + c] = o;
}

// ---------------- fused residual add + LayerNorm (single) --------------------
__global__ __launch_bounds__(128)
void k_add_ln(float* __restrict__ X, u16* __restrict__ Xb,
              const float* __restrict__ Y, const float* __restrict__ g,
              const float* __restrict__ be) {
  int r = blockIdx.x, t = threadIdx.x;
  int c = t * 4;
  f4 x = *(const f4*)&X[(size_t)r * Dn + c];
  f4 y = *(const f4*)&Y[(size_t)r * Dn + c];
  f4 v = x + y;
  float sum = v[0] + v[1] + v[2] + v[3];
  float sq = v[0]*v[0] + v[1]*v[1] + v[2]*v[2] + v[3]*v[3];
  for (int off = 32; off; off >>= 1) {
    sum += __shfl_down(sum, off, 64);
    sq  += __shfl_down(sq,  off, 64);
  }
  __shared__ float red[4];
  int lane = t & 63, w = t >> 6;
  if (!lane) { red[w] = sum; red[2 + w] = sq; }
  __syncthreads();
  sum = red[0] + red[1]; sq = red[2] + red[3];
  float mu = sum * (1.0f / Dn);
  float var = sq * (1.0f / Dn) - mu * mu;
  float rstd = rsqrtf(fmaxf(var, 0.0f) + 1e-5f);
  f4 gg = *(const f4*)&g[c];
  f4 bb = *(const f4*)&be[c];
  f4 o = (v - mu) * rstd * gg + bb;
  *(f4*)&X[(size_t)r * Dn + c] = o;
  us4 ob = { f2bf(o[0]), f2bf(o[1]), f2bf(o[2]), f2bf(o[3]) };
  *(us4*)&Xb[(size_t)r * Dn + c] = ob;
}

// ---------------- fused LN1(X+Y) then LN2(. + CA) ----------------------------
__global__ __launch_bounds__(128)
void k_add_ln12(float* __restrict__ X, u16* __restrict__ Xb,
                const float* __restrict__ Y, const float* __restrict__ CA,
                const float* __restrict__ g1, const float* __restrict__ b1,
                const float* __restrict__ g2, const float* __restrict__ b2) {
  int r = blockIdx.x, t = threadIdx.x;
  int c = t * 4;
  __shared__ float red[8];
  int lane = t & 63, w = t >> 6;
  f4 x = *(const f4*)&X[(size_t)r * Dn + c];
  f4 y = *(const f4*)&Y[(size_t)r * Dn + c];
  f4 v = x + y;
  float sum = v[0] + v[1] + v[2] + v[3];
  float sq = v[0]*v[0] + v[1]*v[1] + v[2]*v[2] + v[3]*v[3];
  for (int off = 32; off; off >>= 1) {
    sum += __shfl_down(sum, off, 64);
    sq  += __shfl_down(sq,  off, 64);
  }
  if (!lane) { red[w] = sum; red[2 + w] = sq; }
  __syncthreads();
  sum = red[0] + red[1]; sq = red[2] + red[3];
  float mu = sum * (1.0f / Dn);
  float var = sq * (1.0f / Dn) - mu * mu;
  float rstd = rsqrtf(fmaxf(var, 0.0f) + 1e-5f);
  f4 g1v = *(const f4*)&g1[c];
  f4 b1v = *(const f4*)&b1[c];
  f4 o1 = (v - mu) * rstd * g1v + b1v;
  f4 ca = *(const f4*)&CA[(size_t)(r >> 7) * Dn + c];
  f4 v2 = o1 + ca;
  float sum2 = v2[0] + v2[1] + v2[2] + v2[3];
  float sq2 = v2[0]*v2[0] + v2[1]*v2[1] + v2[2]*v2[2] + v2[3]*v2[3];
  for (int off = 32; off; off >>= 1) {
    sum2 += __shfl_down(sum2, off, 64);
    sq2  += __shfl_down(sq2,  off, 64);
  }
  if (!lane) { red[4 + w] = sum2; red[6 + w] = sq2; }
  __syncthreads();
  sum2 = red[4] + red[5]; sq2 = red[6] + red[7];
  float mu2 = sum2 * (1.0f / Dn);
  float var2 = sq2 * (1.0f / Dn) - mu2 * mu2;
  float rstd2 = rsqrtf(fmaxf(var2, 0.0f) + 1e-5f);
  f4 g2v = *(const f4*)&g2[c];
  f4 b2v = *(const f4*)&b2[c];
  f4 o2 = (v2 - mu2) * rstd2 * g2v + b2v;
  *(f4*)&X[(size_t)r * Dn + c] = o2;
  us4 ob = { f2bf(o2[0]), f2bf(o2[1]), f2bf(o2[2]), f2bf(o2[3]) };
  *(us4*)&Xb[(size_t)r * Dn + c] = ob;
}

// ---------------- causal self-attention (bf16 QKV in), one (b,h)/block -------
__global__ __launch_bounds__(128)
void k_attn(const u16* __restrict__ QKV, u16* __restrict__ Ob) {
  int bh = blockIdx.x;
  int b = bh >> 3, h = bh & 7;
  int t = threadIdx.x;  // q row
  __shared__ float Ks[Ln][HDn];
  __shared__ float Vs[Ln][HDn];
  __shared__ float Ss[Ln][Ln + 1];
  const u16* base = QKV + (size_t)(b * Ln + t) * 1536;
  const u16* krow = base + 512 + h * HDn;
  const u16* vrow = base + 1024 + h * HDn;
  float q[HDn];
  const u16* qrow = base + h * HDn;
  #pragma unroll
  for (int i = 0; i < HDn; i += 8) {
    short8 kv = *(const short8*)&krow[i];
    short8 vv = *(const short8*)&vrow[i];
    short8 qv = *(const short8*)&qrow[i];
    #pragma unroll
    for (int j = 0; j < 8; j++) {
      Ks[t][i + j] = bf2f((u16)kv[j]);
      Vs[t][i + j] = bf2f((u16)vv[j]);
      q[i + j] = bf2f((u16)qv[j]);
    }
  }
  __syncthreads();
  float m = -1e30f;
  for (int k = 0; k <= t; k++) {
    float s0 = 0, s1 = 0, s2 = 0, s3 = 0;
    #pragma unroll
    for (int i = 0; i < HDn; i += 4) {
      s0 += q[i] * Ks[k][i];     s1 += q[i+1] * Ks[k][i+1];
      s2 += q[i+2] * Ks[k][i+2]; s3 += q[i+3] * Ks[k][i+3];
    }
    float s = (s0 + s1 + s2 + s3) * 0.125f;
    Ss[t][k] = s;
    m = fmaxf(m, s);
  }
  float l = 0.0f;
  for (int k = 0; k <= t; k++) {
    float p = __expf(Ss[t][k] - m);
    Ss[t][k] = p;
    l += p;
  }
  float inv = 1.0f / l;
  float o[HDn] = {0};
  for (int k = 0; k <= t; k++) {
    float p = Ss[t][k];
    #pragma unroll
    for (int i = 0; i < HDn; i += 4) {
      o[i]   += p * Vs[k][i];   o[i+1] += p * Vs[k][i+1];
      o[i+2] += p * Vs[k][i+2]; o[i+3] += p * Vs[k][i+3];
    }
  }
  u16* orow = Ob + (size_t)(b * Ln + t) * Dn + h * HDn;
  #pragma unroll
  for (int i = 0; i < HDn; i += 4) {
    us4 v = { f2bf(o[i] * inv), f2bf(o[i+1] * inv),
              f2bf(o[i+2] * inv), f2bf(o[i+3] * inv) };
    *(us4*)&orow[i] = v;
  }
}

// ---------------- bf16 MFMA GEMM: C = A(MxK) * W(NxK)^T + bias ---------------
// 128xBNT tile, BK=32, 4 waves (2x2). T3-minimum 2-phase double-buffer
// (UNCHANGED sync structure from R4 passing kernel). Transpose buffer Ts is
// ALIASED onto the staging LDS (dead after final K-loop barrier) -> LDS
// 49->32KB (BNT=128), and __launch_bounds__(256,4) -> 4 blocks/CU.
// EPI 0: f32 +bias (col<N masked).  EPI 1: relu(+bias)->bf16.  EPI 2: +bias->bf16.
template <int EPI, int BNT>
__global__ __launch_bounds__(256, 4)
void k_gemm_bt(const u16* __restrict__ A, const u16* __restrict__ Bw,
               const float* __restrict__ bias, void* __restrict__ Cout,
               int gm, int N, int K, int ldc) {
  constexpr int NREP = BNT / 32;
  constexpr int ASTRIDE = 128 * 32;            // u16 per A buffer
  constexpr int BSTRIDE = BNT * 32;            // u16 per B buffer
  constexpr int TSTRIDE = BNT + 4;             // f32 row stride of Ts
  __shared__ __align__(16) char smem[(2 * ASTRIDE + 2 * BSTRIDE) * 2];
  u16* As = (u16*)smem;                        // [2][ASTRIDE]
  u16* Bs = (u16*)(smem + 2 * ASTRIDE * 2);    // [2][BSTRIDE]
  float* Ts = (float*)smem;                    // [2][16][TSTRIDE] aliased

  int lin = blockIdx.x;
  int bm = lin % gm, bn = lin / gm;            // bm fastest
  int tid = threadIdx.x, lane = tid & 63, wid = tid >> 6;
  int wr = wid >> 1, wc = wid & 1;
  f32x4 acc[4][NREP] = {};

  int c0 = tid, c1 = tid + 256;
  const u16* a0 = A + (size_t)(bm * 128 + (c0 >> 2)) * K + (c0 & 3) * 8;
  const u16* a1 = A + (size_t)(bm * 128 + (c1 >> 2)) * K + (c1 & 3) * 8;
  const u16* b0 = Bw + (size_t)(bn * BNT + (c0 >> 2)) * K + (c0 & 3) * 8;
  const u16* b1 = (BNT == 128)
      ? Bw + (size_t)(bn * 128 + (c1 >> 2)) * K + (c1 & 3) * 8 : b0;
  int fr = lane & 15, kq = (lane >> 4) * 8;
  int nt = K >> 5;

  auto stage = [&](int it) {
    int buf = it & 1;
    GLD(a0 + it * 32, (char*)(As + buf * ASTRIDE) + c0 * 16);
    GLD(a1 + it * 32, (char*)(As + buf * ASTRIDE) + c1 * 16);
    GLD(b0 + it * 32, (char*)(Bs + buf * BSTRIDE) + c0 * 16);
    if constexpr (BNT == 128)
      GLD(b1 + it * 32, (char*)(Bs + buf * BSTRIDE) + c1 * 16);
  };

  // prologue: fill buf0, drain, barrier
  stage(0);
  asm volatile("s_waitcnt vmcnt(0)" ::: "memory");
  __builtin_amdgcn_sched_barrier(0);
  __builtin_amdgcn_s_barrier();
  __builtin_amdgcn_sched_barrier(0);

  for (int it = 0; it < nt; ++it) {
    int cur = it & 1;
    if (it + 1 < nt) stage(it + 1);            // writes buf cur^1
    short8 av[4], bv[NREP];
    #pragma unroll
    for (int mi = 0; mi < 4; mi++)
      av[mi] = *(const short8*)&As[cur * ASTRIDE + (wr * 64 + mi * 16 + fr) * 32 + kq];
    #pragma unroll
    for (int nj = 0; nj < NREP; nj++)
      bv[nj] = *(const short8*)&Bs[cur * BSTRIDE + (wc * (BNT / 2) + nj * 16 + fr) * 32 + kq];
    #pragma unroll
    for (int mi = 0; mi < 4; mi++)
      #pragma unroll
      for (int nj = 0; nj < NREP; nj++)
        acc[mi][nj] = __builtin_amdgcn_mfma_f32_16x16x32_bf16(
            av[mi], bv[nj], acc[mi][nj], 0, 0, 0);
    // drain my ds_reads (buf cur) and my staging writes (buf cur^1), then sync
    asm volatile("s_waitcnt vmcnt(0) lgkmcnt(0)" ::: "memory");
    __builtin_amdgcn_sched_barrier(0);
    __builtin_amdgcn_s_barrier();
    __builtin_amdgcn_sched_barrier(0);
  }

  // ---- epilogue: LDS transpose (aliased onto staging LDS) -> coalesced stores
  float bb[NREP];
  #pragma unroll
  for (int nj = 0; nj < NREP; nj++) {
    int cg = bn * BNT + wc * (BNT / 2) + nj * 16 + fr;
    bb[nj] = (cg < N) ? bias[cg] : 0.0f;
  }
  int rl0 = (lane >> 4) * 4;
  #pragma unroll
  for (int mi = 0; mi < 4; mi++) {
    #pragma unroll
    for (int nj = 0; nj < NREP; nj++) {
      int colL = wc * (BNT / 2) + nj * 16 + fr;
      #pragma unroll
      for (int r = 0; r < 4; r++)
        Ts[(wr * 16 + rl0 + r) * TSTRIDE + colL] = acc[mi][nj][r] + bb[nj];
    }
    __syncthreads();
    constexpr int ITERS = (32 * BNT) / 256;
    #pragma unroll
    for (int i = 0; i < ITERS; i++) {
      int flat = i * 256 + tid;
      int rowf = flat / BNT, col = flat % BNT;
      float v = Ts[rowf * TSTRIDE + col];
      int row_g = bm * 128 + (rowf >> 4) * 64 + mi * 16 + (rowf & 15);
      int col_g = bn * BNT + col;
      size_t off = (size_t)row_g * ldc + col_g;
      if (EPI == 0) {
        if (col_g < N) ((float*)Cout)[off] = v;
      } else if (EPI == 1) {
        ((u16*)Cout)[off] = f2bf(fmaxf(v, 0.0f));
      } else {
        ((u16*)Cout)[off] = f2bf(v);
      }
    }
    if (mi < 3) __syncthreads();
  }
}

// =============================================================================
extern "C" void kernel_launch(void* const* d_in, const int* in_sizes, int n_in,
                              void* d_out, int out_size, void* d_ws, size_t ws_size,
                              hipStream_t stream) {
  const float* z        = (const float*)d_in[0];
  const int*   ids      = (const int*)d_in[1];
  const float* tok      = (const float*)d_in[2];
  const float* pos      = (const float*)d_in[3];
  const float* lp_w     = (const float*)d_in[4];
  const float* lp_b     = (const float*)d_in[5];
  const float* lp_g     = (const float*)d_in[6];
  const float* lp_be    = (const float*)d_in[7];
  const float* sa_qkv_w = (const float*)d_in[8];
  const float* sa_qkv_b = (const float*)d_in[9];
  const float* sa_out_w = (const float*)d_in[10];
  const float* sa_out_b = (const float*)d_in[11];
  const float* ca_qkv_w = (const float*)d_in[12];
  const float* ca_qkv_b = (const float*)d_in[13];
  const float* ca_out_w = (const float*)d_in[14];
  const float* ca_out_b = (const float*)d_in[15];
  const float* ln1_g    = (const float*)d_in[16];
  const float* ln1_b    = (const float*)d_in[17];
  const float* ln2_g    = (const float*)d_in[18];
  const float* ln2_b    = (const float*)d_in[19];
  const float* ln3_g    = (const float*)d_in[20];
  const float* ln3_b    = (const float*)d_in[21];
  const float* ff1_w    = (const float*)d_in[22];
  const float* ff1_b    = (const float*)d_in[23];
  const float* ff2_w    = (const float*)d_in[24];
  const float* ff2_b    = (const float*)d_in[25];
  const float* op_w     = (const float*)d_in[26];
  const float* op_b     = (const float*)d_in[27];

  char* ws = (char*)d_ws;
  float* X      = (float*)(ws + 0);           // 4096x512 f32
  float* Y      = (float*)(ws + 8388608);     // 4096x512 f32
  u16*   QKVb   = (u16*)(ws + 16777216);      // 4096x1536 bf16
  u16*   Xb     = (u16*)(ws + 29360128);      // 4096x512 bf16
  u16*   Ob     = (u16*)(ws + 33554432);      // 4096x512 bf16
  u16*   H1b    = (u16*)(ws + 37748736);      // 4096x2048 bf16
  float* mem    = (float*)(ws + 54525952);    // 32x512 f32
  float* ca_add = (float*)(ws + 54657024);    // 4x32x512 f32
  u16*   Wa     = (u16*)(ws + 55050240);      // weight arena bf16

  u16* Wqkv = Wa;                              // 4 x 1536x512
  u16* Wout = Wa + 3145728;                    // 4 x 512x512
  u16* Wff1 = Wa + 4194304;                    // 4 x 2048x512
  u16* Wff2 = Wa + 8388608;                    // 4 x 512x2048
  u16* Wop  = Wa + 12582912;                   // 50304x512 (zero-padded tail)

  auto cvt = [&](const float* src, u16* dst, int n, int npad) {
    int n4 = n / 4, n4p = npad / 4;
    int blocks = (n4p + 255) / 256;
    if (blocks > 2048) blocks = 2048;
    k_cvt_bf16<<<blocks, 256, 0, stream>>>((const f4*)src, (us4*)dst, n4, n4p);
  };

  k_latent_mem<<<Bn, 256, 0, stream>>>(z, lp_w, lp_b, lp_g, lp_be, mem);
  k_ca<<<4 * Bn, 256, 0, stream>>>(mem, ca_qkv_w, ca_qkv_b, ca_out_w, ca_out_b, ca_add);
  k_embed<<<Bn * Ln, 128, 0, stream>>>(ids, tok, pos, X, Xb);
  cvt(sa_qkv_w, Wqkv, 4 * 1536 * Dn, 4 * 1536 * Dn);
  cvt(sa_out_w, Wout, 4 * Dn * Dn, 4 * Dn * Dn);
  cvt(ff1_w,    Wff1, 4 * DFn * Dn, 4 * DFn * Dn);
  cvt(ff2_w,    Wff2, 4 * Dn * DFn, 4 * Dn * DFn);
  cvt(op_w,     Wop,  Vn * Dn, VPAD * Dn);

  const int M = Bn * Ln;  // 4096
  for (int i = 0; i < 4; i++) {
    k_gemm_bt<2, 128><<<32 * 12, 256, 0, stream>>>(
        Xb, Wqkv + (size_t)i * 1536 * Dn, sa_qkv_b + i * 1536, QKVb, 32, 1536, Dn, 1536);
    k_attn<<<Bn * Hn, 128, 0, stream>>>(QKVb, Ob);
    k_gemm_bt<0, 64><<<32 * 8, 256, 0, stream>>>(
        Ob, Wout + (size_t)i * Dn * Dn, sa_out_b + i * Dn, Y, 32, Dn, Dn, Dn);
    k_add_ln12<<<M, 128, 0, stream>>>(X, Xb, Y, ca_add + (size_t)i * Bn * Dn,
                                      ln1_g + i * Dn, ln1_b + i * Dn,
                                      ln2_g + i * Dn, ln2_b + i * Dn);
    k_gemm_bt<1, 128><<<32 * 16, 256, 0, stream>>>(
        Xb, Wff1 + (size_t)i * DFn * Dn, ff1_b + i * DFn, H1b, 32, DFn, Dn, DFn);
    k_gemm_bt<0, 64><<<32 * 8, 256, 0, stream>>>(
        H1b, Wff2 + (size_t)i * Dn * DFn, ff2_b + i * Dn, Y, 32, Dn, DFn, Dn);
    k_add_ln<<<M, 128, 0, stream>>>(X, Xb, Y, ln3_g + i * Dn, ln3_b + i * Dn);
  }

  // final vocab projection -> d_out (f32)
  k_gemm_bt<0, 128><<<32 * 393, 256, 0, stream>>>(
      Xb, Wop, op_b, (float*)d_out, 32, Vn, Dn, Vn);
}

// Round 6
// 1067.959 us; speedup vs baseline: 1.3443x; 1.0865x over previous
//
#include <hip/hip_runtime.h>
#include <math.h>

typedef __attribute__((ext_vector_type(8))) short short8;
typedef __attribute__((ext_vector_type(4))) float f32x4;
typedef __attribute__((ext_vector_type(4))) float f4;
typedef __attribute__((ext_vector_type(4))) unsigned short us4;
typedef unsigned short u16;

#define Bn 32
#define Ln 128
#define Dn 512
#define LATn 256
#define Vn 50257
#define VPAD 50304
#define DFn 2048
#define Hn 8
#define HDn 64

#define GLD(src, dst) __builtin_amdgcn_global_load_lds( \
    (const __attribute__((address_space(1))) unsigned int*)(src), \
    (__attribute__((address_space(3))) unsigned int*)(dst), 16, 0, 0)

__device__ __forceinline__ u16 f2bf(float f) {
  union { float f; unsigned u; } v; v.f = f;
  unsigned r = 0x7FFFu + ((v.u >> 16) & 1u);
  return (u16)((v.u + r) >> 16);
}
__device__ __forceinline__ float bf2f(u16 u) {
  union { unsigned u; float f; } v; v.u = ((unsigned)u) << 16;
  return v.f;
}

// ---------------- f32 -> bf16 conversion (weights), zero-padded tail ---------
__global__ void k_cvt_bf16(const f4* __restrict__ in, us4* __restrict__ out,
                           int n4, int n4pad) {
  int i = blockIdx.x * blockDim.x + threadIdx.x;
  int stride = gridDim.x * blockDim.x;
  for (; i < n4pad; i += stride) {
    us4 o;
    if (i < n4) {
      f4 v = in[i];
      o[0] = f2bf(v[0]); o[1] = f2bf(v[1]); o[2] = f2bf(v[2]); o[3] = f2bf(v[3]);
    } else {
      o[0] = 0; o[1] = 0; o[2] = 0; o[3] = 0;
    }
    out[i] = o;
  }
}

// ---------------- latent_proj: mem = LN(GELU(z @ lp_w.T + lp_b)) -------------
__global__ __launch_bounds__(256)
void k_latent_mem(const float* __restrict__ z, const float* __restrict__ lp_w,
                  const float* __restrict__ lp_b, const float* __restrict__ g,
                  const float* __restrict__ be, float* __restrict__ mem) {
  __shared__ float zs[LATn];
  __shared__ float red[16];
  int b = blockIdx.x, t = threadIdx.x;
  zs[t] = z[b * LATn + t];
  __syncthreads();
  float h[2];
  #pragma unroll
  for (int j = 0; j < 2; j++) {
    int oj = t + j * 256;
    const float* w = lp_w + (size_t)oj * LATn;
    float s0 = 0, s1 = 0, s2 = 0, s3 = 0;
    for (int k = 0; k < LATn; k += 4) {
      s0 += zs[k] * w[k]; s1 += zs[k+1] * w[k+1];
      s2 += zs[k+2] * w[k+2]; s3 += zs[k+3] * w[k+3];
    }
    float x = s0 + s1 + s2 + s3 + lp_b[oj];
    h[j] = 0.5f * x * (1.0f + erff(x * 0.70710678118654752f));
  }
  float sum = h[0] + h[1], sq = h[0]*h[0] + h[1]*h[1];
  for (int off = 32; off; off >>= 1) {
    sum += __shfl_down(sum, off, 64);
    sq  += __shfl_down(sq,  off, 64);
  }
  int lane = t & 63, wid = t >> 6;
  if (!lane) { red[wid] = sum; red[8 + wid] = sq; }
  __syncthreads();
  float ts = red[0] + red[1] + red[2] + red[3];
  float tq = red[8] + red[9] + red[10] + red[11];
  float mu = ts * (1.0f / Dn);
  float var = tq * (1.0f / Dn) - mu * mu;
  float rstd = rsqrtf(fmaxf(var, 0.0f) + 1e-5f);
  #pragma unroll
  for (int j = 0; j < 2; j++) {
    int oj = t + j * 256;
    mem[b * Dn + oj] = (h[j] - mu) * rstd * g[oj] + be[oj];
  }
}

// ------------- cross-attention precompute (Lk=1 => softmax==1 => o = v) ------
__global__ __launch_bounds__(256)
void k_ca(const float* __restrict__ mem, const float* __restrict__ ca_qkv_w,
          const float* __restrict__ ca_qkv_b, const float* __restrict__ ca_out_w,
          const float* __restrict__ ca_out_b, float* __restrict__ ca_add) {
  int blk = blockIdx.x;
  int i = blk >> 5, b = blk & 31, t = threadIdx.x;
  __shared__ float ms[Dn];
  __shared__ float vs[Dn];
  ms[t] = mem[b * Dn + t];
  ms[t + 256] = mem[b * Dn + t + 256];
  __syncthreads();
  const float* wv = ca_qkv_w + ((size_t)i * 1536 + 1024) * Dn;
  const float* bv = ca_qkv_b + i * 1536 + 1024;
  for (int j = t; j < Dn; j += 256) {
    const float* w = wv + (size_t)j * Dn;
    float s0 = 0, s1 = 0, s2 = 0, s3 = 0;
    for (int k = 0; k < Dn; k += 4) {
      s0 += ms[k]*w[k]; s1 += ms[k+1]*w[k+1]; s2 += ms[k+2]*w[k+2]; s3 += ms[k+3]*w[k+3];
    }
    vs[j] = s0 + s1 + s2 + s3 + bv[j];
  }
  __syncthreads();
  const float* wo = ca_out_w + (size_t)i * Dn * Dn;
  const float* bo = ca_out_b + i * Dn;
  for (int j = t; j < Dn; j += 256) {
    const float* w = wo + (size_t)j * Dn;
    float s0 = 0, s1 = 0, s2 = 0, s3 = 0;
    for (int k = 0; k < Dn; k += 4) {
      s0 += vs[k]*w[k]; s1 += vs[k+1]*w[k+1]; s2 += vs[k+2]*w[k+2]; s3 += vs[k+3]*w[k+3];
    }
    ca_add[((size_t)i * Bn + b) * Dn + j] = s0 + s1 + s2 + s3 + bo[j];
  }
}

// ---------------- embedding: X = tok_emb[ids] + pos_emb ----------------------
__global__ __launch_bounds__(128)
void k_embed(const int* __restrict__ ids, const float* __restrict__ tok,
             const float* __restrict__ pos, float* __restrict__ X,
             u16* __restrict__ Xb) {
  int r = blockIdx.x;
  int l = r & (Ln - 1);
  int id = ids[r];
  int c = threadIdx.x * 4;
  f4 te = *(const f4*)&tok[(size_t)id * Dn + c];
  f4 pe = *(const f4*)&pos[(size_t)l * Dn + c];
  f4 v = te + pe;
  *(f4*)&X[(size_t)r * Dn + c] = v;
  us4 o = { f2bf(v[0]), f2bf(v[1]), f2bf(v[2]), f2bf(v[3]) };
  *(us4*)&Xb[(size_t)r * Dn + c] = o;
}

// ---------------- fused residual add + LayerNorm (single) --------------------
__global__ __launch_bounds__(128)
void k_add_ln(float* __restrict__ X, u16* __restrict__ Xb,
              const float* __restrict__ Y, const float* __restrict__ g,
              const float* __restrict__ be) {
  int r = blockIdx.x, t = threadIdx.x;
  int c = t * 4;
  f4 x = *(const f4*)&X[(size_t)r * Dn + c];
  f4 y = *(const f4*)&Y[(size_t)r * Dn + c];
  f4 v = x + y;
  float sum = v[0] + v[1] + v[2] + v[3];
  float sq = v[0]*v[0] + v[1]*v[1] + v[2]*v[2] + v[3]*v[3];
  for (int off = 32; off; off >>= 1) {
    sum += __shfl_down(sum, off, 64);
    sq  += __shfl_down(sq,  off, 64);
  }
  __shared__ float red[4];
  int lane = t & 63, w = t >> 6;
  if (!lane) { red[w] = sum; red[2 + w] = sq; }
  __syncthreads();
  sum = red[0] + red[1]; sq = red[2] + red[3];
  float mu = sum * (1.0f / Dn);
  float var = sq * (1.0f / Dn) - mu * mu;
  float rstd = rsqrtf(fmaxf(var, 0.0f) + 1e-5f);
  f4 gg = *(const f4*)&g[c];
  f4 bb = *(const f4*)&be[c];
  f4 o = (v - mu) * rstd * gg + bb;
  *(f4*)&X[(size_t)r * Dn + c] = o;
  us4 ob = { f2bf(o[0]), f2bf(o[1]), f2bf(o[2]), f2bf(o[3]) };
  *(us4*)&Xb[(size_t)r * Dn + c] = ob;
}

// ---------------- fused LN1(X+Y) then LN2(. + CA) ----------------------------
__global__ __launch_bounds__(128)
void k_add_ln12(float* __restrict__ X, u16* __restrict__ Xb,
                const float* __restrict__ Y, const float* __restrict__ CA,
                const float* __restrict__ g1, const float* __restrict__ b1,
                const float* __restrict__ g2, const float* __restrict__ b2) {
  int r = blockIdx.x, t = threadIdx.x;
  int c = t * 4;
  __shared__ float red[8];
  int lane = t & 63, w = t >> 6;
  f4 x = *(const f4*)&X[(size_t)r * Dn + c];
  f4 y = *(const f4*)&Y[(size_t)r * Dn + c];
  f4 v = x + y;
  float sum = v[0] + v[1] + v[2] + v[3];
  float sq = v[0]*v[0] + v[1]*v[1] + v[2]*v[2] + v[3]*v[3];
  for (int off = 32; off; off >>= 1) {
    sum += __shfl_down(sum, off, 64);
    sq  += __shfl_down(sq,  off, 64);
  }
  if (!lane) { red[w] = sum; red[2 + w] = sq; }
  __syncthreads();
  sum = red[0] + red[1]; sq = red[2] + red[3];
  float mu = sum * (1.0f / Dn);
  float var = sq * (1.0f / Dn) - mu * mu;
  float rstd = rsqrtf(fmaxf(var, 0.0f) + 1e-5f);
  f4 g1v = *(const f4*)&g1[c];
  f4 b1v = *(const f4*)&b1[c];
  f4 o1 = (v - mu) * rstd * g1v + b1v;
  f4 ca = *(const f4*)&CA[(size_t)(r >> 7) * Dn + c];
  f4 v2 = o1 + ca;
  float sum2 = v2[0] + v2[1] + v2[2] + v2[3];
  float sq2 = v2[0]*v2[0] + v2[1]*v2[1] + v2[2]*v2[2] + v2[3]*v2[3];
  for (int off = 32; off; off >>= 1) {
    sum2 += __shfl_down(sum2, off, 64);
    sq2  += __shfl_down(sq2,  off, 64);
  }
  if (!lane) { red[4 + w] = sum2; red[6 + w] = sq2; }
  __syncthreads();
  sum2 = red[4] + red[5]; sq2 = red[6] + red[7];
  float mu2 = sum2 * (1.0f / Dn);
  float var2 = sq2 * (1.0f / Dn) - mu2 * mu2;
  float rstd2 = rsqrtf(fmaxf(var2, 0.0f) + 1e-5f);
  f4 g2v = *(const f4*)&g2[c];
  f4 b2v = *(const f4*)&b2[c];
  f4 o2 = (v2 - mu2) * rstd2 * g2v + b2v;
  *(f4*)&X[(size_t)r * Dn + c] = o2;
  us4 ob = { f2bf(o2[0]), f2bf(o2[1]), f2bf(o2[2]), f2bf(o2[3]) };
  *(us4*)&Xb[(size_t)r * Dn + c] = ob;
}

// ---------------- causal self-attention, split-k: thread=(row, half) ---------
// 256 threads/block, one (b,h)/block. Each thread owns 64 of the 128 k-slots
// of one q-row: halves serial path, doubles waves vs the 1-thread/row version.
// S kept in LDS (no runtime-indexed register arrays). Exact f32 softmax.
__global__ __launch_bounds__(256, 1)
void k_attn2(const u16* __restrict__ QKV, u16* __restrict__ Ob) {
  int bh = blockIdx.x;
  int b = bh >> 3, h = bh & 7;
  int t = threadIdx.x;
  int r = t & 127, half = t >> 7;
  __shared__ float Ks[Ln][HDn + 1];      // 33 KB; aliased as O-combine buffer
  __shared__ float Vs[Ln][HDn + 1];      // 33 KB
  __shared__ float Ss[Ln][Ln + 1];       // 64.5 KB
  __shared__ float Mx[2][Ln];
  __shared__ float Lx[2][Ln];

  const u16* base = QKV + (size_t)(b * Ln + r) * 1536 + h * HDn;
  {  // half 0 stages K row r, half 1 stages V row r (f32 in LDS)
    const u16* src = base + (half ? 1024 : 512);
    float* dst = half ? &Vs[r][0] : &Ks[r][0];
    #pragma unroll
    for (int i = 0; i < HDn; i += 8) {
      short8 v = *(const short8*)&src[i];
      #pragma unroll
      for (int j = 0; j < 8; j++) dst[i + j] = bf2f((u16)v[j]);
    }
  }
  float q[HDn];
  #pragma unroll
  for (int i = 0; i < HDn; i += 8) {
    short8 v = *(const short8*)&base[i];
    #pragma unroll
    for (int j = 0; j < 8; j++) q[i + j] = bf2f((u16)v[j]);
  }
  __syncthreads();

  int kbase = half << 6;
  int nk = r - kbase + 1;
  if (nk < 0) nk = 0;
  if (nk > 64) nk = 64;

  float m = -1e30f;
  for (int j = 0; j < nk; j++) {
    int k = kbase + j;
    float s0 = 0, s1 = 0, s2 = 0, s3 = 0;
    #pragma unroll
    for (int i = 0; i < HDn; i += 4) {
      s0 += q[i] * Ks[k][i];     s1 += q[i+1] * Ks[k][i+1];
      s2 += q[i+2] * Ks[k][i+2]; s3 += q[i+3] * Ks[k][i+3];
    }
    float s = (s0 + s1 + s2 + s3) * 0.125f;
    Ss[r][k] = s;
    m = fmaxf(m, s);
  }
  Mx[half][r] = m;
  __syncthreads();
  float mm = fmaxf(Mx[0][r], Mx[1][r]);
  float l = 0.0f;
  for (int j = 0; j < nk; j++) {
    int k = kbase + j;
    float p = __expf(Ss[r][k] - mm);
    Ss[r][k] = p;
    l += p;
  }
  Lx[half][r] = l;
  __syncthreads();
  float linv = 1.0f / (Lx[0][r] + Lx[1][r]);

  float o[HDn] = {0};
  for (int j = 0; j < nk; j++) {
    int k = kbase + j;
    float p = Ss[r][k];
    #pragma unroll
    for (int i = 0; i < HDn; i += 4) {
      o[i]   += p * Vs[k][i];   o[i+1] += p * Vs[k][i+1];
      o[i+2] += p * Vs[k][i+2]; o[i+3] += p * Vs[k][i+3];
    }
  }
  // combine halves via Ks region (dead since the Mx barrier)
  if (half) {
    #pragma unroll
    for (int i = 0; i < HDn; i++) Ks[r][i] = o[i];
  }
  __syncthreads();
  if (!half) {
    u16* orow = Ob + (size_t)(b * Ln + r) * Dn + h * HDn;
    #pragma unroll
    for (int i = 0; i < HDn; i += 4) {
      us4 v = { f2bf((o[i]   + Ks[r][i])   * linv),
                f2bf((o[i+1] + Ks[r][i+1]) * linv),
                f2bf((o[i+2] + Ks[r][i+2]) * linv),
                f2bf((o[i+3] + Ks[r][i+3]) * linv) };
      *(us4*)&orow[i] = v;
    }
  }
}

// ---------------- bf16 MFMA GEMM: C = A(MxK) * W(NxK)^T + bias ---------------
// 128xBNT tile, BK=32, 4 waves (2x2). True double-buffer with counted vmcnt:
//   stage(it+1); vmcnt(4/3) [= stage(it) landed]; barrier; ds_read+MFMA;
//   lgkmcnt(0); barrier [reads drained -> buffer released].
// Release protocol (lgkmcnt(0)+barrier) is the R4-proven race fix, unchanged.
// Transpose epilogue aliased onto staging LDS. launch_bounds(256,4).
// EPI 0: f32 +bias (col<N masked).  EPI 1: relu(+bias)->bf16.  EPI 2: +bias->bf16.
template <int EPI, int BNT>
__global__ __launch_bounds__(256, 4)
void k_gemm_bt(const u16* __restrict__ A, const u16* __restrict__ Bw,
               const float* __restrict__ bias, void* __restrict__ Cout,
               int gm, int N, int K, int ldc) {
  constexpr int NREP = BNT / 32;
  constexpr int ASTRIDE = 128 * 32;            // u16 per A buffer
  constexpr int BSTRIDE = BNT * 32;            // u16 per B buffer
  constexpr int TSTRIDE = BNT + 4;             // f32 row stride of Ts
  __shared__ __align__(16) char smem[(2 * ASTRIDE + 2 * BSTRIDE) * 2];
  u16* As = (u16*)smem;                        // [2][ASTRIDE]
  u16* Bs = (u16*)(smem + 2 * ASTRIDE * 2);    // [2][BSTRIDE]
  float* Ts = (float*)smem;                    // [2][16][TSTRIDE] aliased

  int lin = blockIdx.x;
  int bm = lin % gm, bn = lin / gm;            // bm fastest
  int tid = threadIdx.x, lane = tid & 63, wid = tid >> 6;
  int wr = wid >> 1, wc = wid & 1;
  f32x4 acc[4][NREP] = {};

  int c0 = tid, c1 = tid + 256;
  const u16* a0 = A + (size_t)(bm * 128 + (c0 >> 2)) * K + (c0 & 3) * 8;
  const u16* a1 = A + (size_t)(bm * 128 + (c1 >> 2)) * K + (c1 & 3) * 8;
  const u16* b0 = Bw + (size_t)(bn * BNT + (c0 >> 2)) * K + (c0 & 3) * 8;
  const u16* b1 = (BNT == 128)
      ? Bw + (size_t)(bn * 128 + (c1 >> 2)) * K + (c1 & 3) * 8 : b0;
  int fr = lane & 15, kq = (lane >> 4) * 8;
  int nt = K >> 5;

  auto stage = [&](int it) {
    int buf = it & 1;
    GLD(a0 + it * 32, (char*)(As + buf * ASTRIDE) + c0 * 16);
    GLD(a1 + it * 32, (char*)(As + buf * ASTRIDE) + c1 * 16);
    GLD(b0 + it * 32, (char*)(Bs + buf * BSTRIDE) + c0 * 16);
    if constexpr (BNT == 128)
      GLD(b1 + it * 32, (char*)(Bs + buf * BSTRIDE) + c1 * 16);
  };

  stage(0);
  for (int it = 0; it < nt; ++it) {
    int cur = it & 1;
    if (it + 1 < nt) {
      stage(it + 1);                            // writes buf cur^1 (released last iter)
      // wait for stage(it): only stage(it+1)'s loads may remain outstanding
      if constexpr (BNT == 128) asm volatile("s_waitcnt vmcnt(4)" ::: "memory");
      else                      asm volatile("s_waitcnt vmcnt(3)" ::: "memory");
    } else {
      asm volatile("s_waitcnt vmcnt(0)" ::: "memory");
    }
    __builtin_amdgcn_sched_barrier(0);
    __builtin_amdgcn_s_barrier();               // buf cur ready for all waves
    __builtin_amdgcn_sched_barrier(0);
    short8 av[4], bv[NREP];
    #pragma unroll
    for (int mi = 0; mi < 4; mi++)
      av[mi] = *(const short8*)&As[cur * ASTRIDE + (wr * 64 + mi * 16 + fr) * 32 + kq];
    #pragma unroll
    for (int nj = 0; nj < NREP; nj++)
      bv[nj] = *(const short8*)&Bs[cur * BSTRIDE + (wc * (BNT / 2) + nj * 16 + fr) * 32 + kq];
    #pragma unroll
    for (int mi = 0; mi < 4; mi++)
      #pragma unroll
      for (int nj = 0; nj < NREP; nj++)
        acc[mi][nj] = __builtin_amdgcn_mfma_f32_16x16x32_bf16(
            av[mi], bv[nj], acc[mi][nj], 0, 0, 0);
    asm volatile("s_waitcnt lgkmcnt(0)" ::: "memory");  // my reads of buf cur done
    __builtin_amdgcn_sched_barrier(0);
    __builtin_amdgcn_s_barrier();               // buf cur released for restage
    __builtin_amdgcn_sched_barrier(0);
  }

  // ---- epilogue: LDS transpose (aliased onto staging LDS) -> coalesced stores
  float bb[NREP];
  #pragma unroll
  for (int nj = 0; nj < NREP; nj++) {
    int cg = bn * BNT + wc * (BNT / 2) + nj * 16 + fr;
    bb[nj] = (cg < N) ? bias[cg] : 0.0f;
  }
  int rl0 = (lane >> 4) * 4;
  #pragma unroll
  for (int mi = 0; mi < 4; mi++) {
    #pragma unroll
    for (int nj = 0; nj < NREP; nj++) {
      int colL = wc * (BNT / 2) + nj * 16 + fr;
      #pragma unroll
      for (int r = 0; r < 4; r++)
        Ts[(wr * 16 + rl0 + r) * TSTRIDE + colL] = acc[mi][nj][r] + bb[nj];
    }
    __syncthreads();
    constexpr int ITERS = (32 * BNT) / 256;
    #pragma unroll
    for (int i = 0; i < ITERS; i++) {
      int flat = i * 256 + tid;
      int rowf = flat / BNT, col = flat % BNT;
      float v = Ts[rowf * TSTRIDE + col];
      int row_g = bm * 128 + (rowf >> 4) * 64 + mi * 16 + (rowf & 15);
      int col_g = bn * BNT + col;
      size_t off = (size_t)row_g * ldc + col_g;
      if (EPI == 0) {
        if (col_g < N) ((float*)Cout)[off] = v;
      } else if (EPI == 1) {
        ((u16*)Cout)[off] = f2bf(fmaxf(v, 0.0f));
      } else {
        ((u16*)Cout)[off] = f2bf(v);
      }
    }
    if (mi < 3) __syncthreads();
  }
}

// =============================================================================
extern "C" void kernel_launch(void* const* d_in, const int* in_sizes, int n_in,
                              void* d_out, int out_size, void* d_ws, size_t ws_size,
                              hipStream_t stream) {
  const float* z        = (const float*)d_in[0];
  const int*   ids      = (const int*)d_in[1];
  const float* tok      = (const float*)d_in[2];
  const float* pos      = (const float*)d_in[3];
  const float* lp_w     = (const float*)d_in[4];
  const float* lp_b     = (const float*)d_in[5];
  const float* lp_g     = (const float*)d_in[6];
  const float* lp_be    = (const float*)d_in[7];
  const float* sa_qkv_w = (const float*)d_in[8];
  const float* sa_qkv_b = (const float*)d_in[9];
  const float* sa_out_w = (const float*)d_in[10];
  const float* sa_out_b = (const float*)d_in[11];
  const float* ca_qkv_w = (const float*)d_in[12];
  const float* ca_qkv_b = (const float*)d_in[13];
  const float* ca_out_w = (const float*)d_in[14];
  const float* ca_out_b = (const float*)d_in[15];
  const float* ln1_g    = (const float*)d_in[16];
  const float* ln1_b    = (const float*)d_in[17];
  const float* ln2_g    = (const float*)d_in[18];
  const float* ln2_b    = (const float*)d_in[19];
  const float* ln3_g    = (const float*)d_in[20];
  const float* ln3_b    = (const float*)d_in[21];
  const float* ff1_w    = (const float*)d_in[22];
  const float* ff1_b    = (const float*)d_in[23];
  const float* ff2_w    = (const float*)d_in[24];
  const float* ff2_b    = (const float*)d_in[25];
  const float* op_w     = (const float*)d_in[26];
  const float* op_b     = (const float*)d_in[27];

  char* ws = (char*)d_ws;
  float* X      = (float*)(ws + 0);           // 4096x512 f32
  float* Y      = (float*)(ws + 8388608);     // 4096x512 f32
  u16*   QKVb   = (u16*)(ws + 16777216);      // 4096x1536 bf16
  u16*   Xb     = (u16*)(ws + 29360128);      // 4096x512 bf16
  u16*   Ob     = (u16*)(ws + 33554432);      // 4096x512 bf16
  u16*   H1b    = (u16*)(ws + 37748736);      // 4096x2048 bf16
  float* mem    = (float*)(ws + 54525952);    // 32x512 f32
  float* ca_add = (float*)(ws + 54657024);    // 4x32x512 f32
  u16*   Wa     = (u16*)(ws + 55050240);      // weight arena bf16

  u16* Wqkv = Wa;                              // 4 x 1536x512
  u16* Wout = Wa + 3145728;                    // 4 x 512x512
  u16* Wff1 = Wa + 4194304;                    // 4 x 2048x512
  u16* Wff2 = Wa + 8388608;                    // 4 x 512x2048
  u16* Wop  = Wa + 12582912;                   // 50304x512 (zero-padded tail)

  auto cvt = [&](const float* src, u16* dst, int n, int npad) {
    int n4 = n / 4, n4p = npad / 4;
    int blocks = (n4p + 255) / 256;
    if (blocks > 2048) blocks = 2048;
    k_cvt_bf16<<<blocks, 256, 0, stream>>>((const f4*)src, (us4*)dst, n4, n4p);
  };

  k_latent_mem<<<Bn, 256, 0, stream>>>(z, lp_w, lp_b, lp_g, lp_be, mem);
  k_ca<<<4 * Bn, 256, 0, stream>>>(mem, ca_qkv_w, ca_qkv_b, ca_out_w, ca_out_b, ca_add);
  k_embed<<<Bn * Ln, 128, 0, stream>>>(ids, tok, pos, X, Xb);
  cvt(sa_qkv_w, Wqkv, 4 * 1536 * Dn, 4 * 1536 * Dn);
  cvt(sa_out_w, Wout, 4 * Dn * Dn, 4 * Dn * Dn);
  cvt(ff1_w,    Wff1, 4 * DFn * Dn, 4 * DFn * Dn);
  cvt(ff2_w,    Wff2, 4 * Dn * DFn, 4 * Dn * DFn);
  cvt(op_w,     Wop,  Vn * Dn, VPAD * Dn);

  const int M = Bn * Ln;  // 4096
  for (int i = 0; i < 4; i++) {
    k_gemm_bt<2, 128><<<32 * 12, 256, 0, stream>>>(
        Xb, Wqkv + (size_t)i * 1536 * Dn, sa_qkv_b + i * 1536, QKVb, 32, 1536, Dn, 1536);
    k_attn2<<<Bn * Hn, 256, 0, stream>>>(QKVb, Ob);
    k_gemm_bt<0, 64><<<32 * 8, 256, 0, stream>>>(
        Ob, Wout + (size_t)i * Dn * Dn, sa_out_b + i * Dn, Y, 32, Dn, Dn, Dn);
    k_add_ln12<<<M, 128, 0, stream>>>(X, Xb, Y, ca_add + (size_t)i * Bn * Dn,
                                      ln1_g + i * Dn, ln1_b + i * Dn,
                                      ln2_g + i * Dn, ln2_b + i * Dn);
    k_gemm_bt<1, 128><<<32 * 16, 256, 0, stream>>>(
        Xb, Wff1 + (size_t)i * DFn * Dn, ff1_b + i * DFn, H1b, 32, DFn, Dn, DFn);
    k_gemm_bt<0, 64><<<32 * 8, 256, 0, stream>>>(
        H1b, Wff2 + (size_t)i * Dn * DFn, ff2_b + i * Dn, Y, 32, Dn, DFn, Dn);
    k_add_ln<<<M, 128, 0, stream>>>(X, Xb, Y, ln3_g + i * Dn, ln3_b + i * Dn);
  }

  // final vocab projection -> d_out (f32)
  k_gemm_bt<0, 128><<<32 * 393, 256, 0, stream>>>(
      Xb, Wop, op_b, (float*)d_out, 32, Vn, Dn, Vn);
}